// Round 2
// baseline (2293.115 us; speedup 1.0000x reference)
//
#include <hip/hip_runtime.h>
#include <cstdint>

// Seq2Seq GRU encoder/decoder with attention, batch=1, L=50, H=1024, T=128.
// Latency-bound sequential chain -> one persistent cooperative kernel,
// 256 WGs x 256 threads (1 per CU), flag-based sync with agent-scope atomics.
//
// Roles: WG0 = attention (aw), WG1 = output projection + loss (1 step behind),
// WG2..5 = o-helpers (o = relu(pre_comb + M@aw)), WG6..255 = GRU producers.

#define HDIM 1024
#define LSEQ 50
#define TDIM 128
#define G3   3072

struct KArgs {
  const int* input_ids; const int* tag_ids;
  const float* word_embed;
  const float* enc_Wih; const float* enc_Whh; const float* enc_bih; const float* enc_bhh;
  const float* dec_embed; const float* attn_W; const float* attn_b;
  const float* comb_W; const float* comb_b;
  const float* dec_Wih; const float* dec_Whh; const float* dec_bih; const float* dec_bhh;
  const float* out_W; const float* out_b;
  float* out;
  unsigned* flags;   // 256 per-WG monotonic phase counters
  unsigned* flagA;   // aw ready (WG0), value t+1
  unsigned* flagO4;  // 4 helper o-slice flags, value t+1
  float* GI;         // 50*3072 enc gi (bih folded)
  float* attn_e;     // 50*50  (attn_b folded)
  float* pre_comb;   // 50*1024 (comb_b folded)
  float* M;          // 1024*50  comb_W[:,H:] @ enc_outs^T
  float* enc_outs;   // 50*1024
  float* hbuf0; float* hbuf1;   // h ping-pong
  float* obuf0; float* obuf1;   // o ping-pong
  float* awbuf;      // 2*64
};

// ---- agent-scope (cross-XCD coherent) accessors: bypass non-coherent L2s ----
__device__ __forceinline__ float ld_coh(const float* p){
  return __hip_atomic_load(p, __ATOMIC_RELAXED, __HIP_MEMORY_SCOPE_AGENT);
}
__device__ __forceinline__ void st_coh(float* p, float v){
  __hip_atomic_store(p, v, __ATOMIC_RELAXED, __HIP_MEMORY_SCOPE_AGENT);
}
__device__ __forceinline__ unsigned ldf(const unsigned* p){
  return __hip_atomic_load(p, __ATOMIC_RELAXED, __HIP_MEMORY_SCOPE_AGENT);
}
__device__ __forceinline__ void stf(unsigned* p, unsigned v){
  __hip_atomic_store(p, v, __ATOMIC_RELEASE, __HIP_MEMORY_SCOPE_AGENT);
}

__device__ __forceinline__ float wred_sum(float v){
  #pragma unroll
  for(int o=32;o>0;o>>=1) v += __shfl_xor(v,o,64);
  return v;
}
__device__ __forceinline__ float wred_max(float v){
  #pragma unroll
  for(int o=32;o>0;o>>=1) v = fmaxf(v,__shfl_xor(v,o,64));
  return v;
}

struct Chunk { float4 a,b,c,d; };
__device__ __forceinline__ Chunk load_chunk(const float* __restrict__ row, int lane){
  const float4* p = reinterpret_cast<const float4*>(row) + lane*4;
  Chunk w; w.a=p[0]; w.b=p[1]; w.c=p[2]; w.d=p[3]; return w;
}
__device__ __forceinline__ float chunk_dot(const Chunk& w, const float* hc){
  return w.a.x*hc[0]+w.a.y*hc[1]+w.a.z*hc[2]+w.a.w*hc[3]
       + w.b.x*hc[4]+w.b.y*hc[5]+w.b.z*hc[6]+w.b.w*hc[7]
       + w.c.x*hc[8]+w.c.y*hc[9]+w.c.z*hc[10]+w.c.w*hc[11]
       + w.d.x*hc[12]+w.d.y*hc[13]+w.d.z*hc[14]+w.d.w*hc[15];
}
__device__ __forceinline__ void load_vec16(const float* __restrict__ v, float* hc, int lane){
  const float4* p = reinterpret_cast<const float4*>(v) + lane*4;
  float4 x0=p[0],x1=p[1],x2=p[2],x3=p[3];
  hc[0]=x0.x; hc[1]=x0.y; hc[2]=x0.z; hc[3]=x0.w;
  hc[4]=x1.x; hc[5]=x1.y; hc[6]=x1.z; hc[7]=x1.w;
  hc[8]=x2.x; hc[9]=x2.y; hc[10]=x2.z; hc[11]=x2.w;
  hc[12]=x3.x; hc[13]=x3.y; hc[14]=x3.z; hc[15]=x3.w;
}
__device__ __forceinline__ void load_coh16(const float* v, float* hc, int lane){
  const float* p = v + lane*16;
  #pragma unroll
  for(int k=0;k<16;k++) hc[k]=ld_coh(p+k);
}
__device__ __forceinline__ float sigm(float x){ return 1.f/(1.f+expf(-x)); }

// wait until flags[i] >= tgt for all i in [skip,256)
__device__ __forceinline__ void wait_all(const unsigned* flags, unsigned tgt, int skip, int lane){
  for(;;){
    unsigned f0 = (lane>=skip) ? ldf(flags+lane) : 0xFFFFFFFFu;
    unsigned f1 = ldf(flags+64+lane);
    unsigned f2 = ldf(flags+128+lane);
    unsigned f3 = ldf(flags+192+lane);
    bool ok = (f0>=tgt)&&(f1>=tgt)&&(f2>=tgt)&&(f3>=tgt);
    if(__all(ok)) return;
    __builtin_amdgcn_s_sleep(2);
  }
}
__device__ __forceinline__ void wait_one(const unsigned* p, unsigned tgt, int lane){
  for(;;){
    unsigned f = (lane==0)?ldf(p):0u;
    f = (unsigned)__shfl((int)f,0,64);
    if(f>=tgt) return;
    __builtin_amdgcn_s_sleep(1);
  }
}
__device__ __forceinline__ void wait4(const unsigned* p, unsigned tgt, int lane){
  for(;;){
    unsigned f = (lane<4)?ldf(p+lane):0xFFFFFFFFu;
    if(__all((int)(f>=tgt))) return;
    __builtin_amdgcn_s_sleep(1);
  }
}

__global__ __launch_bounds__(256) void seq2seq_kernel(KArgs A){
  const int bid = blockIdx.x;
  const int tid = threadIdx.x;
  const int wave = tid>>6, lane = tid&63;
  __shared__ float sm[256];

  float* hb[2] = {A.hbuf0, A.hbuf1};
  float* ob[2] = {A.obuf0, A.obuf1};

  // ================= phase 1: prologue (all token-dependent precompute) ======
  {
    const int gv = bid*4 + wave;  // global wave id 0..1023
    // (a) encoder gi for all steps: GI[te][row] = enc_Wih[row]·emb[src[te]] + bih[row]
    #pragma unroll
    for(int rr=0; rr<3; ++rr){
      const int row = gv*3+rr;
      Chunk w = load_chunk(A.enc_Wih + (size_t)row*HDIM, lane);
      const float bi = A.enc_bih[row];
      for(int te=0;te<LSEQ;++te){
        const int tok = A.input_ids[te];
        float ec[16]; load_vec16(A.word_embed + (size_t)tok*HDIM, ec, lane);
        float d = wred_sum(chunk_dot(w,ec));
        if(lane==0) st_coh(&A.GI[te*G3+row], d + bi);
      }
    }
    // (b) attn_e[t][s] = attn_W[s][:H]·e_t + attn_b[s]
    if(gv < LSEQ){
      const int s = gv;
      Chunk w = load_chunk(A.attn_W + (size_t)s*2*HDIM, lane);
      const float bb = A.attn_b[s];
      for(int t=0;t<LSEQ;++t){
        const int tok = (t==0)?1:A.tag_ids[t-1];
        float ec[16]; load_vec16(A.dec_embed + (size_t)tok*HDIM, ec, lane);
        float d = wred_sum(chunk_dot(w,ec));
        if(lane==0) st_coh(&A.attn_e[t*LSEQ+s], d + bb);
      }
    }
    // (c) pre_comb[t][i] = comb_W[i][:H]·e_t + comb_b[i]
    {
      const int i = gv;
      Chunk w = load_chunk(A.comb_W + (size_t)i*2*HDIM, lane);
      const float bb = A.comb_b[i];
      for(int t=0;t<LSEQ;++t){
        const int tok = (t==0)?1:A.tag_ids[t-1];
        float ec[16]; load_vec16(A.dec_embed + (size_t)tok*HDIM, ec, lane);
        float d = wred_sum(chunk_dot(w,ec));
        if(lane==0) st_coh(&A.pre_comb[t*HDIM+i], d + bb);
      }
    }
    __syncthreads();
    if(tid==0) stf(&A.flags[bid], 1u);
  }

  // producer geometry: WGs 6..255 own h elements
  const int p = bid - 6;
  int ne=0, base=0;
  if(p>=0){ if(p<24){ ne=5; base=p*5; } else { ne=4; base=120+(p-24)*4; } }

  // ================= encoder: 50 sequential GRU steps (producers only) =======
  if(p>=0){
    for(int te=0;te<LSEQ;++te){
      wait_all(A.flags, 1u+te, (te==0)?0:6, lane);
      float hc[16];
      if(te>0){
        load_coh16(hb[(te+1)&1], hc, lane);
      } else {
        for(int k=0;k<16;k++) hc[k]=0.f;
      }
      const int nr = 3*ne;
      for(int r=wave;r<nr;r+=4){
        const int le=r/3, g=r-le*3, row=g*HDIM+base+le;
        Chunk w = load_chunk(A.enc_Whh + (size_t)row*HDIM, lane);
        float d = wred_sum(chunk_dot(w,hc));
        if(lane==0) sm[r] = d;
      }
      __syncthreads();
      if(tid<ne){
        const int j = base+tid;
        float gr = sm[tid*3]   + A.enc_bhh[j];
        float gz = sm[tid*3+1] + A.enc_bhh[HDIM+j];
        float gn = sm[tid*3+2] + A.enc_bhh[2*HDIM+j];
        const float* GIr = A.GI + te*G3;
        float ir = GIr[j], iz = GIr[HDIM+j], inn = GIr[2*HDIM+j];
        float hj = (te>0)? ld_coh(&hb[(te+1)&1][j]) : 0.f;
        float r_ = sigm(ir+gr), z_ = sigm(iz+gz);
        float n_ = tanhf(inn + r_*gn);
        float h2 = (1.f-z_)*n_ + z_*hj;
        st_coh(&hb[te&1][j], h2);
        st_coh(&A.enc_outs[te*HDIM+j], h2);
      }
      __syncthreads();
      if(tid==0) stf(&A.flags[bid], 2u+te);
    }
  }

  // ================= M = comb_W[:,H:] @ enc_outs^T (all WGs) =================
  {
    wait_all(A.flags, 51u, 6, lane);
    const int i = bid*4 + wave;
    Chunk w = load_chunk(A.comb_W + (size_t)i*2*HDIM + HDIM, lane);
    for(int s=0;s<LSEQ;++s){
      float ec[16]; load_vec16(A.enc_outs + s*HDIM, ec, lane);
      float d = wred_sum(chunk_dot(w,ec));
      if(lane==0) st_coh(&A.M[(size_t)i*LSEQ+s], d);
    }
    __syncthreads();
    if(tid==0) stf(&A.flags[bid], 52u);
  }

  // ================= decoder: 50 steps ======================================
  if(bid==0){
    // attention: logits -> softmax -> aw broadcast
    for(int t=0;t<LSEQ;++t){
      wait_all(A.flags, 52u+t, (t==0)?0:6, lane);
      float hc[16]; load_coh16(hb[(t+1)&1], hc, lane);
      const int s0 = wave*13, scnt = (wave<3)?13:11;
      for(int q=0;q<scnt;++q){
        const int s = s0+q;
        Chunk w = load_chunk(A.attn_W + (size_t)s*2*HDIM + HDIM, lane);
        float d = wred_sum(chunk_dot(w,hc));
        if(lane==0) sm[s] = d + A.attn_e[t*LSEQ+s];
      }
      __syncthreads();
      if(wave==0){
        float l = (lane<LSEQ)? sm[lane] : -1e30f;
        float m = wred_max(l);
        float pe = (lane<LSEQ)? expf(l-m) : 0.f;
        float ss = wred_sum(pe);
        if(lane<LSEQ) st_coh(&A.awbuf[(t&1)*64+lane], pe/ss);
      }
      __syncthreads();
      if(tid==0) stf(A.flagA, (unsigned)(t+1));
    }
  } else if(bid>=2 && bid<6){
    // o-helpers: o = relu(pre_comb[t] + M@aw), slice of 256
    const int hi = bid-2;
    for(int t=0;t<LSEQ;++t){
      wait_one(A.flagA, (unsigned)(t+1), lane);
      if(tid<LSEQ) sm[tid] = ld_coh(&A.awbuf[(t&1)*64+tid]);
      __syncthreads();
      const int i = hi*256 + tid;
      const float* Mi = A.M + (size_t)i*LSEQ;
      float acc = A.pre_comb[t*HDIM+i];
      for(int s=0;s<LSEQ;++s) acc += Mi[s]*sm[s];
      st_coh(&ob[t&1][i], fmaxf(acc,0.f));
      __syncthreads();
      if(tid==0) stf(&A.flagO4[hi], (unsigned)(t+1));
    }
  } else if(bid==1){
    // output projection + double log_softmax + loss (one step behind)
    float loss = 0.f;
    for(int t=0;t<LSEQ;++t){
      wait_all(A.flags, 53u+t, 6, lane);
      float hc[16]; load_coh16(hb[t&1], hc, lane);
      for(int s=wave;s<TDIM;s+=4){
        Chunk w = load_chunk(A.out_W + (size_t)s*HDIM, lane);
        float d = wred_sum(chunk_dot(w,hc));
        if(lane==0) sm[s] = d + A.out_b[s];
      }
      __syncthreads();
      if(wave==0){
        float l0 = sm[lane], l1 = sm[lane+64];
        float m  = wred_max(fmaxf(l0,l1));
        float pe = expf(l0-m)+expf(l1-m);
        float s1 = wred_sum(pe);
        float lse = m + logf(s1);
        float lp0 = l0-lse, lp1 = l1-lse;
        float m2  = wred_max(fmaxf(lp0,lp1));
        float p2  = expf(lp0-m2)+expf(lp1-m2);
        float s2  = wred_sum(p2);
        float lse2 = m2 + logf(s2);
        A.out[t*TDIM + lane]      = lp0;
        A.out[t*TDIM + 64 + lane] = lp1;
        const int tg = A.tag_ids[t];
        float c = ((lane==tg)?(lse2-lp0):0.f) + ((lane+64==tg)?(lse2-lp1):0.f);
        c = wred_sum(c);
        if(tg != 0) loss += c;
      }
      __syncthreads();
    }
    if(tid==0) A.out[LSEQ*TDIM] = loss;
  } else if(p>=0){
    // producers: gh (overlaps aw/o chain), then gi, GRU combine -> h2
    for(int t=0;t<LSEQ;++t){
      wait_all(A.flags, 52u+t, (t==0)?0:6, lane);
      const float* hsrc = hb[(t+1)&1];
      float hc[16]; load_coh16(hsrc, hc, lane);
      const int nr = 3*ne;
      for(int r=wave;r<nr;r+=4){
        const int le=r/3, g=r-le*3, row=g*HDIM+base+le;
        Chunk w = load_chunk(A.dec_Whh + (size_t)row*HDIM, lane);
        float d = wred_sum(chunk_dot(w,hc));
        if(lane==0) sm[r] = d;
      }
      wait4(A.flagO4, (unsigned)(t+1), lane);
      float oc[16]; load_coh16(ob[t&1], oc, lane);
      for(int r=wave;r<nr;r+=4){
        const int le=r/3, g=r-le*3, row=g*HDIM+base+le;
        Chunk w = load_chunk(A.dec_Wih + (size_t)row*HDIM, lane);
        float d = wred_sum(chunk_dot(w,oc));
        if(lane==0) sm[16+r] = d;
      }
      __syncthreads();
      if(tid<ne){
        const int j = base+tid;
        float gr = sm[tid*3]      + A.dec_bhh[j];
        float gz = sm[tid*3+1]    + A.dec_bhh[HDIM+j];
        float gn = sm[tid*3+2]    + A.dec_bhh[2*HDIM+j];
        float ir = sm[16+tid*3]   + A.dec_bih[j];
        float iz = sm[16+tid*3+1] + A.dec_bih[HDIM+j];
        float inn= sm[16+tid*3+2] + A.dec_bih[2*HDIM+j];
        float hj = ld_coh(&hsrc[j]);
        float r_ = sigm(ir+gr), z_ = sigm(iz+gz);
        float n_ = tanhf(inn + r_*gn);
        float h2 = (1.f-z_)*n_ + z_*hj;
        st_coh(&hb[t&1][j], h2);
      }
      __syncthreads();
      if(tid==0) stf(&A.flags[bid], 53u+t);
    }
  }
}

extern "C" void kernel_launch(void* const* d_in, const int* in_sizes, int n_in,
                              void* d_out, int out_size, void* d_ws, size_t ws_size,
                              hipStream_t stream){
  (void)in_sizes; (void)n_in; (void)out_size; (void)ws_size;
  KArgs A;
  A.input_ids = (const int*)d_in[0];
  A.tag_ids   = (const int*)d_in[1];
  A.word_embed= (const float*)d_in[2];
  A.enc_Wih   = (const float*)d_in[3];
  A.enc_Whh   = (const float*)d_in[4];
  A.enc_bih   = (const float*)d_in[5];
  A.enc_bhh   = (const float*)d_in[6];
  A.dec_embed = (const float*)d_in[7];
  A.attn_W    = (const float*)d_in[8];
  A.attn_b    = (const float*)d_in[9];
  A.comb_W    = (const float*)d_in[10];
  A.comb_b    = (const float*)d_in[11];
  A.dec_Wih   = (const float*)d_in[12];
  A.dec_Whh   = (const float*)d_in[13];
  A.dec_bih   = (const float*)d_in[14];
  A.dec_bhh   = (const float*)d_in[15];
  A.out_W     = (const float*)d_in[16];
  A.out_b     = (const float*)d_in[17];
  A.out       = (float*)d_out;

  unsigned* u = (unsigned*)d_ws;
  A.flags  = u;
  A.flagA  = u + 256;
  A.flagO4 = u + 257;
  float* f = (float*)d_ws + 512;
  A.GI       = f; f += 153600;
  A.attn_e   = f; f += 2560;
  A.pre_comb = f; f += 51200;
  A.M        = f; f += 51200;
  A.enc_outs = f; f += 51200;
  A.hbuf0    = f; f += 1024;
  A.hbuf1    = f; f += 1024;
  A.obuf0    = f; f += 1024;
  A.obuf1    = f; f += 1024;
  A.awbuf    = f; f += 128;

  (void)hipMemsetAsync(d_ws, 0, 2048, stream);
  void* args[] = { &A };
  (void)hipLaunchCooperativeKernel((const void*)seq2seq_kernel, dim3(256), dim3(256),
                                   args, 0, stream);
}

// Round 3
// 2083.798 us; speedup vs baseline: 1.1004x; 1.1004x over previous
//
#include <hip/hip_runtime.h>
#include <cstdint>

// Seq2Seq GRU enc/dec with attention, batch=1, L=50, H=1024, T=128 (fp32).
// One persistent cooperative kernel, 256 WGs x 256 threads.
// Roles: WG0..3 = attention+o helpers (redundant aw, o slice each),
//        WG4 = output projection + loss (1 step behind),
//        WG5 = idle after prologue/M, WG6..255 = 250 GRU producers.
// Sync: 4 spread atomic counters per barrier (class = bid&3), wave0 polls.
// Cross-WG data: sc0 sc1 (device-coherent) dwordx4 loads staged via LDS.

#define HDIM 1024
#define LSEQ 50
#define TDIM 128
#define G3   3072
#define PB   6

typedef float f32x4 __attribute__((ext_vector_type(4)));

struct KArgs {
  const int* input_ids; const int* tag_ids;
  const float* word_embed;
  const float* enc_Wih; const float* enc_Whh; const float* enc_bih; const float* enc_bhh;
  const float* dec_embed; const float* attn_W; const float* attn_b;
  const float* comb_W; const float* comb_b;
  const float* dec_Wih; const float* dec_Whh; const float* dec_bih; const float* dec_bhh;
  const float* out_W; const float* out_b;
  float* out;
  unsigned* ctrP; unsigned* ctrE; unsigned* ctrM; unsigned* ctrH; unsigned* flagO;
  float* GI;        // 50*3072
  float* attn_e;    // 50*50
  float* pre_comb;  // 50*1024
  float* MT;        // 50*1024 (transposed: MT[s*H+i])
  float* enc_outs;  // 50*1024
  float* hbE;       // 2*1024 encoder ping-pong
  float* hbD;       // 3*1024 decoder tri-buffer
  float* obD;       // 2*1024 o ping-pong
};

// ---- device-coherent accessors (visible across XCDs via IF) ----
__device__ __forceinline__ void st_coh(float* p, float v){
  __hip_atomic_store(p, v, __ATOMIC_RELAXED, __HIP_MEMORY_SCOPE_AGENT);
}
__device__ __forceinline__ void stf(unsigned* p, unsigned v){
  __hip_atomic_store(p, v, __ATOMIC_RELEASE, __HIP_MEMORY_SCOPE_AGENT);
}
__device__ __forceinline__ void addc(unsigned* base, int bid){
  __hip_atomic_fetch_add(base + (bid&3)*16, 1u, __ATOMIC_RELEASE, __HIP_MEMORY_SCOPE_AGENT);
}
__device__ __forceinline__ f32x4 coh_load4(const float* p){
  f32x4 v;
  asm volatile("global_load_dwordx4 %0, %1, off sc0 sc1\n\ts_waitcnt vmcnt(0)"
               : "=v"(v) : "v"(p) : "memory");
  return v;
}

__device__ __forceinline__ float wred_sum(float v){
  #pragma unroll
  for(int o=32;o>0;o>>=1) v += __shfl_xor(v,o,64);
  return v;
}
__device__ __forceinline__ float wred_max(float v){
  #pragma unroll
  for(int o=32;o>0;o>>=1) v = fmaxf(v,__shfl_xor(v,o,64));
  return v;
}

struct Chunk { float4 a,b,c,d; };
__device__ __forceinline__ Chunk load_chunk(const float* __restrict__ row, int lane){
  const float4* p = reinterpret_cast<const float4*>(row) + lane*4;
  Chunk w; w.a=p[0]; w.b=p[1]; w.c=p[2]; w.d=p[3]; return w;
}
__device__ __forceinline__ float chunk_dot(const Chunk& w, const float* hc){
  return w.a.x*hc[0]+w.a.y*hc[1]+w.a.z*hc[2]+w.a.w*hc[3]
       + w.b.x*hc[4]+w.b.y*hc[5]+w.b.z*hc[6]+w.b.w*hc[7]
       + w.c.x*hc[8]+w.c.y*hc[9]+w.c.z*hc[10]+w.c.w*hc[11]
       + w.d.x*hc[12]+w.d.y*hc[13]+w.d.z*hc[14]+w.d.w*hc[15];
}
__device__ __forceinline__ void load_vec16(const float* __restrict__ v, float* hc, int lane){
  const float4* p = reinterpret_cast<const float4*>(v) + lane*4;
  float4 x0=p[0],x1=p[1],x2=p[2],x3=p[3];
  hc[0]=x0.x; hc[1]=x0.y; hc[2]=x0.z; hc[3]=x0.w;
  hc[4]=x1.x; hc[5]=x1.y; hc[6]=x1.z; hc[7]=x1.w;
  hc[8]=x2.x; hc[9]=x2.y; hc[10]=x2.z; hc[11]=x2.w;
  hc[12]=x3.x; hc[13]=x3.y; hc[14]=x3.z; hc[15]=x3.w;
}
__device__ __forceinline__ float sigm(float x){ return 1.f/(1.f+expf(-x)); }

// stage 1024-float vector: thread t coherent-loads g[4t..4t+3], writes LDS
// transposed: element j -> lds[(j&15)*64 + (j>>4)] (conflict-free read16)
__device__ __forceinline__ void stage_vec(float* ldsb, const float* g, int tid){
  f32x4 v = coh_load4(g + 4*tid);
  int q = tid>>2, r4 = (tid&3)*4;
  ldsb[(r4+0)*64+q]=v.x; ldsb[(r4+1)*64+q]=v.y;
  ldsb[(r4+2)*64+q]=v.z; ldsb[(r4+3)*64+q]=v.w;
}
__device__ __forceinline__ void read16(const float* ldsb, float* hc, int lane){
  #pragma unroll
  for(int k=0;k<16;k++) hc[k]=ldsb[k*64+lane];
}

// wave0-only poll: lanes 0..3 check counter class c >= tgt (tgt=0 for lane>=4)
__device__ __forceinline__ void wait_ctr(const unsigned* base, unsigned tgt, int lane){
  const unsigned* p = base + lane*16;
  for(;;){
    unsigned v = (lane<4)? __hip_atomic_load(p,__ATOMIC_RELAXED,__HIP_MEMORY_SCOPE_AGENT) : 0u;
    if(__all((int)(v>=tgt))) return;
    __builtin_amdgcn_s_sleep(2);
  }
}
// producer classes (bids 6..255): counts per class {62,62,63,63}
__device__ __forceinline__ unsigned tgt_prod(unsigned mult,int lane){
  return (lane<4)? (62u+((lane>>1)&1u))*mult : 0u;
}
__device__ __forceinline__ unsigned tgt_all(unsigned mult,int lane){
  return (lane<4)? 64u*mult : 0u;
}
__device__ __forceinline__ unsigned tgt_one(unsigned mult,int lane){
  return (lane<4)? mult : 0u;
}

__global__ __launch_bounds__(256) void seq2seq_kernel(KArgs A){
  const int bid = blockIdx.x, tid = threadIdx.x;
  const int wave = tid>>6, lane = tid&63;
  __shared__ float lds_h[HDIM];
  __shared__ float lds_o[HDIM];
  __shared__ float smr[64];
  __shared__ float smL[TDIM];
  __shared__ float awL[64];

  const int gv = bid*4 + wave;   // global wave id 0..1023

  // ================= prologue: token-dependent precompute ====================
  {
    const int r0 = gv*3;
    Chunk w0 = load_chunk(A.enc_Wih + (size_t)r0*HDIM, lane);
    Chunk w1 = load_chunk(A.enc_Wih + (size_t)(r0+1)*HDIM, lane);
    Chunk w2 = load_chunk(A.enc_Wih + (size_t)(r0+2)*HDIM, lane);
    float b0=A.enc_bih[r0], b1=A.enc_bih[r0+1], b2=A.enc_bih[r0+2];
    for(int te=0;te<LSEQ;++te){
      int tok = A.input_ids[te];
      float ec[16]; load_vec16(A.word_embed + (size_t)tok*HDIM, ec, lane);
      float d0 = wred_sum(chunk_dot(w0,ec));
      float d1 = wred_sum(chunk_dot(w1,ec));
      float d2 = wred_sum(chunk_dot(w2,ec));
      if(lane==0){
        st_coh(&A.GI[te*G3+r0],   d0+b0);
        st_coh(&A.GI[te*G3+r0+1], d1+b1);
        st_coh(&A.GI[te*G3+r0+2], d2+b2);
      }
    }
    Chunk wc = load_chunk(A.comb_W + (size_t)gv*2*HDIM, lane);
    float bc = A.comb_b[gv];
    Chunk wa; wa.a=make_float4(0,0,0,0); wa.b=wa.a; wa.c=wa.a; wa.d=wa.a;
    float ba = 0.f;
    if(gv < LSEQ){ wa = load_chunk(A.attn_W + (size_t)gv*2*HDIM, lane); ba = A.attn_b[gv]; }
    for(int t=0;t<LSEQ;++t){
      int tok = (t==0)?1:A.tag_ids[t-1];
      float ec[16]; load_vec16(A.dec_embed + (size_t)tok*HDIM, ec, lane);
      float dc = wred_sum(chunk_dot(wc,ec));
      if(lane==0) st_coh(&A.pre_comb[t*HDIM+gv], dc+bc);
      if(gv < LSEQ){
        float da = wred_sum(chunk_dot(wa,ec));
        if(lane==0) st_coh(&A.attn_e[t*LSEQ+gv], da+ba);
      }
    }
  }
  __syncthreads();
  if(tid==0) addc(A.ctrP, bid);
  if(wave==0) wait_ctr(A.ctrP, tgt_all(1,lane), lane);
  __syncthreads();

  // producer geometry
  const int p = bid - PB;
  int ne=0, base=0;
  if(p>=0){ ne=(p<24)?5:4; base=(p<24)? p*5 : 120+(p-24)*4; }
  const int nr = 3*ne;

  // ================= encoder: 50 sequential GRU steps ========================
  if(p>=0){
    for(int te=0;te<LSEQ;++te){
      if(te>0){
        if(wave==0) wait_ctr(A.ctrE, tgt_prod((unsigned)te,lane), lane);
        __syncthreads();
        stage_vec(lds_h, A.hbE + ((te-1)&1)*HDIM, tid);
      }
      __syncthreads();
      float hc[16];
      if(te>0) read16(lds_h, hc, lane);
      else     { for(int k=0;k<16;k++) hc[k]=0.f; }
      for(int r=wave;r<nr;r+=4){
        int le=r/3, g=r-le*3, row=g*HDIM+base+le;
        float d = wred_sum(chunk_dot(load_chunk(A.enc_Whh+(size_t)row*HDIM,lane),hc));
        if(lane==0) smr[r]=d;
      }
      __syncthreads();
      if(tid<ne){
        int j = base+tid;
        float gr=smr[tid*3]+A.enc_bhh[j], gz=smr[tid*3+1]+A.enc_bhh[HDIM+j],
              gn=smr[tid*3+2]+A.enc_bhh[2*HDIM+j];
        const float* GIr = A.GI + te*G3;
        float hj = (te>0)? lds_h[((j&15)<<6)+(j>>4)] : 0.f;
        float r_=sigm(GIr[j]+gr), z_=sigm(GIr[HDIM+j]+gz);
        float n_=tanhf(GIr[2*HDIM+j]+r_*gn);
        float h2=(1.f-z_)*n_+z_*hj;
        st_coh(&A.hbE[(te&1)*HDIM+j], h2);
        st_coh(&A.enc_outs[te*HDIM+j], h2);
        if(te==LSEQ-1) st_coh(&A.hbD[j], h2);
      }
      __syncthreads();
      if(tid==0) addc(A.ctrE, bid);
    }
  }

  // ================= MT = comb_W[:,H:] @ enc_outs^T (transposed store) =======
  if(wave==0) wait_ctr(A.ctrE, tgt_prod(LSEQ,lane), lane);
  __syncthreads();
  {
    Chunk wm = load_chunk(A.comb_W + (size_t)gv*2*HDIM + HDIM, lane);
    for(int s=0;s<LSEQ;++s){
      float ec[16]; load_vec16(A.enc_outs + s*HDIM, ec, lane);
      float d = wred_sum(chunk_dot(wm,ec));
      if(lane==0) st_coh(&A.MT[s*HDIM+gv], d);
    }
  }
  __syncthreads();
  if(tid==0) addc(A.ctrM, bid);
  if(wave==0) wait_ctr(A.ctrM, tgt_all(1,lane), lane);
  __syncthreads();

  // ================= decoder: 50 steps =======================================
  if(bid < 4){
    // helpers: redundant aw, then o slice [bid*256 .. +256)
    const int hi = bid;
    for(int t=0;t<LSEQ;++t){
      if(t>0){ if(wave==0) wait_ctr(A.ctrH, tgt_prod((unsigned)t,lane), lane); }
      __syncthreads();
      stage_vec(lds_h, A.hbD + (t%3)*HDIM, tid);
      __syncthreads();
      float hc[16]; read16(lds_h, hc, lane);
      const int s0=wave*13, scnt=(wave<3)?13:11;
      for(int q=0;q<scnt;++q){
        int s=s0+q;
        float d = wred_sum(chunk_dot(load_chunk(A.attn_W+(size_t)s*2*HDIM+HDIM,lane),hc));
        if(lane==0) smL[s] = d + A.attn_e[t*LSEQ+s];
      }
      __syncthreads();
      if(wave==0){
        float l = (lane<LSEQ)? smL[lane] : -1e30f;
        float m = wred_max(l);
        float pe = (lane<LSEQ)? expf(l-m) : 0.f;
        float ss = wred_sum(pe);
        awL[lane] = (lane<LSEQ)? pe/ss : 0.f;
      }
      __syncthreads();
      {
        int i = hi*256 + tid;
        float acc = A.pre_comb[t*HDIM+i];
        for(int s=0;s<LSEQ;++s) acc += A.MT[s*HDIM+i]*awL[s];
        st_coh(&A.obD[(t&1)*HDIM+i], fmaxf(acc,0.f));
      }
      __syncthreads();
      if(tid==0) stf(A.flagO + hi*16, (unsigned)(t+1));
    }
  } else if(bid == 4){
    // output projection + double log_softmax + loss (1 step behind)
    float loss = 0.f;
    for(int t=0;t<LSEQ;++t){
      if(wave==0) wait_ctr(A.ctrH, tgt_prod((unsigned)(t+1),lane), lane);
      __syncthreads();
      stage_vec(lds_h, A.hbD + ((t+1)%3)*HDIM, tid);
      __syncthreads();
      float hc[16]; read16(lds_h, hc, lane);
      for(int s=wave;s<TDIM;s+=4){
        float d = wred_sum(chunk_dot(load_chunk(A.out_W+(size_t)s*HDIM,lane),hc));
        if(lane==0) smL[s] = d + A.out_b[s];
      }
      __syncthreads();
      if(wave==0){
        float l0=smL[lane], l1=smL[lane+64];
        float m  = wred_max(fmaxf(l0,l1));
        float pe = expf(l0-m)+expf(l1-m);
        float s1 = wred_sum(pe);
        float lse = m + logf(s1);
        float lp0 = l0-lse, lp1 = l1-lse;
        float m2  = wred_max(fmaxf(lp0,lp1));
        float p2  = expf(lp0-m2)+expf(lp1-m2);
        float s2  = wred_sum(p2);
        float lse2 = m2 + logf(s2);
        A.out[t*TDIM + lane]      = lp0;
        A.out[t*TDIM + 64 + lane] = lp1;
        int tg = A.tag_ids[t];
        float c = ((lane==tg)?(lse2-lp0):0.f) + ((lane+64==tg)?(lse2-lp1):0.f);
        c = wred_sum(c);
        if(tg != 0) loss += c;
      }
      __syncthreads();
    }
    if(tid==0) A.out[LSEQ*TDIM] = loss;
  } else if(p >= 0){
    // producers
    for(int t=0;t<LSEQ;++t){
      if(t>0){ if(wave==0) wait_ctr(A.ctrH, tgt_prod((unsigned)t,lane), lane); }
      __syncthreads();
      stage_vec(lds_h, A.hbD + (t%3)*HDIM, tid);
      __syncthreads();
      float hc[16]; read16(lds_h, hc, lane);
      for(int r=wave;r<nr;r+=4){
        int le=r/3, g=r-le*3, row=g*HDIM+base+le;
        float d = wred_sum(chunk_dot(load_chunk(A.dec_Whh+(size_t)row*HDIM,lane),hc));
        if(lane==0) smr[r]=d;
      }
      if(wave==0) wait_ctr(A.flagO, tgt_one((unsigned)(t+1),lane), lane);
      __syncthreads();
      stage_vec(lds_o, A.obD + (t&1)*HDIM, tid);
      __syncthreads();
      float oc[16]; read16(lds_o, oc, lane);
      for(int r=wave;r<nr;r+=4){
        int le=r/3, g=r-le*3, row=g*HDIM+base+le;
        float d = wred_sum(chunk_dot(load_chunk(A.dec_Wih+(size_t)row*HDIM,lane),oc));
        if(lane==0) smr[32+r]=d;
      }
      __syncthreads();
      if(tid<ne){
        int j = base+tid;
        float gr=smr[tid*3]+A.dec_bhh[j],      gz=smr[tid*3+1]+A.dec_bhh[HDIM+j],
              gn=smr[tid*3+2]+A.dec_bhh[2*HDIM+j];
        float ir=smr[32+tid*3]+A.dec_bih[j],   iz=smr[32+tid*3+1]+A.dec_bih[HDIM+j],
              inn=smr[32+tid*3+2]+A.dec_bih[2*HDIM+j];
        float hj = lds_h[((j&15)<<6)+(j>>4)];
        float r_=sigm(ir+gr), z_=sigm(iz+gz);
        float n_=tanhf(inn+r_*gn);
        float h2=(1.f-z_)*n_+z_*hj;
        st_coh(&A.hbD[((t+1)%3)*HDIM+j], h2);
      }
      __syncthreads();
      if(tid==0) addc(A.ctrH, bid);
    }
  }
}

extern "C" void kernel_launch(void* const* d_in, const int* in_sizes, int n_in,
                              void* d_out, int out_size, void* d_ws, size_t ws_size,
                              hipStream_t stream){
  (void)in_sizes; (void)n_in; (void)out_size; (void)ws_size;
  KArgs A;
  A.input_ids = (const int*)d_in[0];
  A.tag_ids   = (const int*)d_in[1];
  A.word_embed= (const float*)d_in[2];
  A.enc_Wih   = (const float*)d_in[3];
  A.enc_Whh   = (const float*)d_in[4];
  A.enc_bih   = (const float*)d_in[5];
  A.enc_bhh   = (const float*)d_in[6];
  A.dec_embed = (const float*)d_in[7];
  A.attn_W    = (const float*)d_in[8];
  A.attn_b    = (const float*)d_in[9];
  A.comb_W    = (const float*)d_in[10];
  A.comb_b    = (const float*)d_in[11];
  A.dec_Wih   = (const float*)d_in[12];
  A.dec_Whh   = (const float*)d_in[13];
  A.dec_bih   = (const float*)d_in[14];
  A.dec_bhh   = (const float*)d_in[15];
  A.out_W     = (const float*)d_in[16];
  A.out_b     = (const float*)d_in[17];
  A.out       = (float*)d_out;

  unsigned* u = (unsigned*)d_ws;
  A.ctrP  = u;         // classes at +0,16,32,48 (64B apart)
  A.ctrE  = u + 64;
  A.ctrM  = u + 128;
  A.ctrH  = u + 192;
  A.flagO = u + 256;   // 4 flags at +0,16,32,48
  float* f = (float*)d_ws + 512;
  A.GI       = f; f += LSEQ*G3;
  A.attn_e   = f; f += LSEQ*LSEQ + 14;   // pad
  A.pre_comb = f; f += LSEQ*HDIM;
  A.MT       = f; f += LSEQ*HDIM;
  A.enc_outs = f; f += LSEQ*HDIM;
  A.hbE      = f; f += 2*HDIM;
  A.hbD      = f; f += 3*HDIM;
  A.obD      = f; f += 2*HDIM;

  (void)hipMemsetAsync(d_ws, 0, 2048, stream);
  void* args[] = { &A };
  (void)hipLaunchCooperativeKernel((const void*)seq2seq_kernel, dim3(256), dim3(256),
                                   args, 0, stream);
}

// Round 4
// 1109.389 us; speedup vs baseline: 2.0670x; 1.8783x over previous
//
#include <hip/hip_runtime.h>
#include <cstdint>

// Seq2Seq GRU enc/dec with attention, batch=1, L=50, H=1024, T=128 (fp32).
// Persistent cooperative kernel, 256 WGs x 256 threads, 1 WG/CU.
// WG0..3 helpers (redundant aw + o slice), WG4 out-proj+loss (1 behind),
// WG5 idle, WG6..255 producers (own 4-5 h elements).
// Critical-path matvec weights held in VGPRs across all 50 steps; all
// wave reductions batched (independent shuffle chains interleaved).

#define HDIM 1024
#define LSEQ 50
#define TDIM 128
#define G3   3072
#define PB   6
#define LSTR 68

typedef float f32x4 __attribute__((ext_vector_type(4)));

struct KArgs {
  const int* input_ids; const int* tag_ids;
  const float* word_embed;
  const float* enc_Wih; const float* enc_Whh; const float* enc_bih; const float* enc_bhh;
  const float* dec_embed; const float* attn_W; const float* attn_b;
  const float* comb_W; const float* comb_b;
  const float* dec_Wih; const float* dec_Whh; const float* dec_bih; const float* dec_bhh;
  const float* out_W; const float* out_b;
  float* out;
  unsigned* ctrP; unsigned* ctrE; unsigned* ctrM; unsigned* ctrH; unsigned* flagO;
  unsigned* ctrW;
  float* GI;        // 50*3072
  float* attn_e;    // 50*50
  float* pre_comb;  // 50*1024
  float* MT;        // 50*1024 (MT[s*H+i])
  float* enc_outs;  // 50*1024
  float* hbE;       // 2*1024
  float* hbD;       // 3*1024
  float* obD;       // 2*1024
};

__device__ __forceinline__ void st_coh(float* p, float v){
  __hip_atomic_store(p, v, __ATOMIC_RELAXED, __HIP_MEMORY_SCOPE_AGENT);
}
__device__ __forceinline__ void stf(unsigned* p, unsigned v){
  __hip_atomic_store(p, v, __ATOMIC_RELEASE, __HIP_MEMORY_SCOPE_AGENT);
}
__device__ __forceinline__ void addc(unsigned* base, int bid){
  __hip_atomic_fetch_add(base + (bid&3)*16, 1u, __ATOMIC_RELEASE, __HIP_MEMORY_SCOPE_AGENT);
}
__device__ __forceinline__ f32x4 coh_load4(const float* p){
  f32x4 v;
  asm volatile("global_load_dwordx4 %0, %1, off sc0 sc1\n\ts_waitcnt vmcnt(0)"
               : "=v"(v) : "v"(p) : "memory");
  return v;
}

template<int N>
__device__ __forceinline__ void wred_batch(float* v){
  #pragma unroll
  for(int o=32;o>0;o>>=1){
    #pragma unroll
    for(int i=0;i<N;i++) v[i] += __shfl_xor(v[i],o,64);
  }
}
__device__ __forceinline__ float wred_sum(float v){
  #pragma unroll
  for(int o=32;o>0;o>>=1) v += __shfl_xor(v,o,64);
  return v;
}
__device__ __forceinline__ float wred_max(float v){
  #pragma unroll
  for(int o=32;o>0;o>>=1) v = fmaxf(v,__shfl_xor(v,o,64));
  return v;
}

struct Chunk { float4 a,b,c,d; };
__device__ __forceinline__ Chunk load_chunk(const float* __restrict__ row, int lane){
  const float4* p = reinterpret_cast<const float4*>(row) + lane*4;
  Chunk w; w.a=p[0]; w.b=p[1]; w.c=p[2]; w.d=p[3]; return w;
}
__device__ __forceinline__ float chunk_dot(const Chunk& w, const float* hc){
  return w.a.x*hc[0]+w.a.y*hc[1]+w.a.z*hc[2]+w.a.w*hc[3]
       + w.b.x*hc[4]+w.b.y*hc[5]+w.b.z*hc[6]+w.b.w*hc[7]
       + w.c.x*hc[8]+w.c.y*hc[9]+w.c.z*hc[10]+w.c.w*hc[11]
       + w.d.x*hc[12]+w.d.y*hc[13]+w.d.z*hc[14]+w.d.w*hc[15];
}
__device__ __forceinline__ void load_vec16(const float* __restrict__ v, float* hc, int lane){
  const float4* p = reinterpret_cast<const float4*>(v) + lane*4;
  float4 x0=p[0],x1=p[1],x2=p[2],x3=p[3];
  hc[0]=x0.x; hc[1]=x0.y; hc[2]=x0.z; hc[3]=x0.w;
  hc[4]=x1.x; hc[5]=x1.y; hc[6]=x1.z; hc[7]=x1.w;
  hc[8]=x2.x; hc[9]=x2.y; hc[10]=x2.z; hc[11]=x2.w;
  hc[12]=x3.x; hc[13]=x3.y; hc[14]=x3.z; hc[15]=x3.w;
}
__device__ __forceinline__ float sigm(float x){ return 1.f/(1.f+expf(-x)); }

// stage 1024 floats: thread t coherent-loads g[4t..4t+3] -> padded LDS
// element j -> lds[(j&15)*LSTR + (j>>4)]   (2-way max on read & write)
__device__ __forceinline__ void stage_vec(float* ldsb, const float* g, int tid){
  f32x4 v = coh_load4(g + 4*tid);
  int q = tid>>2, r4 = (tid&3)*4;
  ldsb[(r4+0)*LSTR+q]=v.x; ldsb[(r4+1)*LSTR+q]=v.y;
  ldsb[(r4+2)*LSTR+q]=v.z; ldsb[(r4+3)*LSTR+q]=v.w;
}
__device__ __forceinline__ void read16(const float* ldsb, float* hc, int lane){
  #pragma unroll
  for(int k=0;k<16;k++) hc[k]=ldsb[k*LSTR+lane];
}

__device__ __forceinline__ void wait_ctr(const unsigned* base, unsigned tgt, int lane){
  const unsigned* p = base + lane*16;
  for(;;){
    unsigned v = (lane<4)? __hip_atomic_load(p,__ATOMIC_RELAXED,__HIP_MEMORY_SCOPE_AGENT) : 0u;
    if(__all((int)(v>=tgt))) return;
    __builtin_amdgcn_s_sleep(1);
  }
}
__device__ __forceinline__ unsigned tgt_prod(unsigned mult,int lane){
  return (lane<4)? (62u+((lane>>1)&1u))*mult : 0u;
}
__device__ __forceinline__ unsigned tgt_all(unsigned mult,int lane){
  return (lane<4)? 64u*mult : 0u;
}
__device__ __forceinline__ unsigned tgt_one(unsigned mult,int lane){
  return (lane<4)? mult : 0u;
}
__device__ __forceinline__ unsigned tgt_lane0(unsigned mult,int lane){
  return (lane==0)? mult : 0u;
}

__global__ __launch_bounds__(256,1) void seq2seq_kernel(KArgs A){
  const int bid = blockIdx.x, tid = threadIdx.x;
  const int wave = tid>>6, lane = tid&63;
  __shared__ float lds_h[16*LSTR+16];
  __shared__ float lds_o[16*LSTR+16];
  __shared__ float smr[64];
  __shared__ float smL[TDIM];
  __shared__ float awL[64];

  const int gv = bid*4 + wave;   // 0..1023

  // ================= prologue ================================================
  {
    const int r0 = gv*3;
    Chunk w0 = load_chunk(A.enc_Wih + (size_t)r0*HDIM, lane);
    Chunk w1 = load_chunk(A.enc_Wih + (size_t)(r0+1)*HDIM, lane);
    Chunk w2 = load_chunk(A.enc_Wih + (size_t)(r0+2)*HDIM, lane);
    float b0=A.enc_bih[r0], b1=A.enc_bih[r0+1], b2=A.enc_bih[r0+2];
    for(int te=0;te<LSEQ;++te){
      int tok = A.input_ids[te];
      float ec[16]; load_vec16(A.word_embed + (size_t)tok*HDIM, ec, lane);
      float d[3];
      d[0]=chunk_dot(w0,ec); d[1]=chunk_dot(w1,ec); d[2]=chunk_dot(w2,ec);
      wred_batch<3>(d);
      if(lane==0){
        st_coh(&A.GI[te*G3+r0],   d[0]+b0);
        st_coh(&A.GI[te*G3+r0+1], d[1]+b1);
        st_coh(&A.GI[te*G3+r0+2], d[2]+b2);
      }
    }
    Chunk wc = load_chunk(A.comb_W + (size_t)gv*2*HDIM, lane);
    float bc = A.comb_b[gv];
    Chunk wa; wa.a=make_float4(0,0,0,0); wa.b=wa.a; wa.c=wa.a; wa.d=wa.a;
    float ba = 0.f;
    if(gv < LSEQ){ wa = load_chunk(A.attn_W + (size_t)gv*2*HDIM, lane); ba = A.attn_b[gv]; }
    for(int t=0;t<LSEQ;++t){
      int tok = (t==0)?1:A.tag_ids[t-1];
      float ec[16]; load_vec16(A.dec_embed + (size_t)tok*HDIM, ec, lane);
      float d[2];
      d[0]=chunk_dot(wc,ec);
      d[1]=(gv<LSEQ)? chunk_dot(wa,ec) : 0.f;
      wred_batch<2>(d);
      if(lane==0){
        st_coh(&A.pre_comb[t*HDIM+gv], d[0]+bc);
        if(gv<LSEQ) st_coh(&A.attn_e[t*LSEQ+gv], d[1]+ba);
      }
    }
  }
  __syncthreads();
  if(tid==0) addc(A.ctrP, bid);
  if(wave==0) wait_ctr(A.ctrP, tgt_all(1,lane), lane);
  __syncthreads();

  // producer geometry
  const int p = bid - PB;
  int ne=0, base=0;
  if(p>=0){ ne=(p<24)?5:4; base=(p<24)? p*5 : 120+(p-24)*4; }
  const int nr = 3*ne;

  // ================= encoder =================================================
  if(p>=0){
    // hoist this wave's enc_Whh rows into registers (<=4 rows)
    Chunk we[4];
    #pragma unroll
    for(int i=0;i<4;i++){
      int r = wave+4*i; int rc = (r<nr)? r : 0;
      int le=rc/3, g=rc-le*3, row=g*HDIM+base+le;
      we[i] = load_chunk(A.enc_Whh + (size_t)row*HDIM, lane);
    }
    for(int te=0;te<LSEQ;++te){
      if(te>0){
        if(wave==0) wait_ctr(A.ctrE, tgt_prod((unsigned)te,lane), lane);
        __syncthreads();
        stage_vec(lds_h, A.hbE + ((te-1)&1)*HDIM, tid);
      }
      __syncthreads();
      float hc[16];
      if(te>0) read16(lds_h, hc, lane);
      else     { for(int k=0;k<16;k++) hc[k]=0.f; }
      float part[4];
      #pragma unroll
      for(int i=0;i<4;i++) part[i]=chunk_dot(we[i],hc);
      wred_batch<4>(part);
      if(lane==0){
        #pragma unroll
        for(int i=0;i<4;i++){ int r=wave+4*i; if(r<nr) smr[r]=part[i]; }
      }
      __syncthreads();
      if(tid<ne){
        int j = base+tid;
        float gr=smr[tid*3]+A.enc_bhh[j], gz=smr[tid*3+1]+A.enc_bhh[HDIM+j],
              gn=smr[tid*3+2]+A.enc_bhh[2*HDIM+j];
        const float* GIr = A.GI + te*G3;
        float hj = (te>0)? lds_h[((j&15)*LSTR)+(j>>4)] : 0.f;
        float r_=sigm(GIr[j]+gr), z_=sigm(GIr[HDIM+j]+gz);
        float n_=tanhf(GIr[2*HDIM+j]+r_*gn);
        float h2=(1.f-z_)*n_+z_*hj;
        st_coh(&A.hbE[(te&1)*HDIM+j], h2);
        st_coh(&A.enc_outs[te*HDIM+j], h2);
        if(te==LSEQ-1) st_coh(&A.hbD[j], h2);
      }
      __syncthreads();
      if(tid==0) addc(A.ctrE, bid);
    }
  }

  // ================= MT = comb_W[:,H:] @ enc_outs^T ==========================
  if(wave==0) wait_ctr(A.ctrE, tgt_prod(LSEQ,lane), lane);
  __syncthreads();
  {
    Chunk wm = load_chunk(A.comb_W + (size_t)gv*2*HDIM + HDIM, lane);
    for(int sg=0;sg<10;++sg){
      float pt[5];
      #pragma unroll
      for(int j=0;j<5;j++){
        float ec[16]; load_vec16(A.enc_outs + (sg*5+j)*HDIM, ec, lane);
        pt[j]=chunk_dot(wm,ec);
      }
      wred_batch<5>(pt);
      if(lane==0){
        #pragma unroll
        for(int j=0;j<5;j++) st_coh(&A.MT[(sg*5+j)*HDIM+gv], pt[j]);
      }
    }
  }
  __syncthreads();
  if(tid==0) addc(A.ctrM, bid);
  if(wave==0) wait_ctr(A.ctrM, tgt_all(1,lane), lane);
  __syncthreads();

  // ================= decoder =================================================
  if(bid < 4){
    const int hi = bid;
    // hoist attn_W[:,H:] rows: s = wave+4*i, i=0..12
    Chunk wa7[7], wa6[6];
    #pragma unroll
    for(int i=0;i<7;i++){ int s=wave+4*i;
      wa7[i]=load_chunk(A.attn_W+(size_t)s*2*HDIM+HDIM,lane); }
    #pragma unroll
    for(int i=0;i<6;i++){ int s=wave+28+4*i; int sc=(s<LSEQ)?s:0;
      wa6[i]=load_chunk(A.attn_W+(size_t)sc*2*HDIM+HDIM,lane); }
    for(int t=0;t<LSEQ;++t){
      if(t>0){ if(wave==0) wait_ctr(A.ctrH, tgt_prod((unsigned)t,lane), lane); }
      __syncthreads();
      stage_vec(lds_h, A.hbD + (t%3)*HDIM, tid);
      __syncthreads();
      float hc[16]; read16(lds_h, hc, lane);
      {
        float p7[7];
        #pragma unroll
        for(int i=0;i<7;i++) p7[i]=chunk_dot(wa7[i],hc);
        wred_batch<7>(p7);
        if(lane==0){
          #pragma unroll
          for(int i=0;i<7;i++){ int s=wave+4*i; smL[s]=p7[i]+A.attn_e[t*LSEQ+s]; }
        }
        float p6[6];
        #pragma unroll
        for(int i=0;i<6;i++) p6[i]=chunk_dot(wa6[i],hc);
        wred_batch<6>(p6);
        if(lane==0){
          #pragma unroll
          for(int i=0;i<6;i++){ int s=wave+28+4*i; if(s<LSEQ) smL[s]=p6[i]+A.attn_e[t*LSEQ+s]; }
        }
      }
      __syncthreads();
      if(wave==0){
        float l = (lane<LSEQ)? smL[lane] : -1e30f;
        float m = wred_max(l);
        float pe = (lane<LSEQ)? expf(l-m) : 0.f;
        float ss = wred_sum(pe);
        awL[lane] = (lane<LSEQ)? pe/ss : 0.f;
      }
      __syncthreads();
      {
        int i = hi*256 + tid;
        const float* Mi = A.MT + i;
        float acc = A.pre_comb[t*HDIM+i];
        #pragma unroll 10
        for(int s=0;s<LSEQ;++s) acc += Mi[s*HDIM]*awL[s];
        st_coh(&A.obD[(t&1)*HDIM+i], fmaxf(acc,0.f));
      }
      __syncthreads();
      if(tid==0) stf(A.flagO + hi*16, (unsigned)(t+1));
    }
  } else if(bid == 4){
    float loss = 0.f;
    for(int t=0;t<LSEQ;++t){
      if(wave==0) wait_ctr(A.ctrH, tgt_prod((unsigned)(t+1),lane), lane);
      __syncthreads();
      stage_vec(lds_h, A.hbD + ((t+1)%3)*HDIM, tid);
      __syncthreads();
      if(tid==0) stf(A.ctrW, (unsigned)(t+1));   // staged step t's h
      float hc[16]; read16(lds_h, hc, lane);
      for(int g8=0; g8<4; ++g8){
        Chunk w[8]; float pt[8];
        #pragma unroll
        for(int i=0;i<8;i++){ int s=wave+4*(g8*8+i);
          w[i]=load_chunk(A.out_W+(size_t)s*HDIM,lane); }
        #pragma unroll
        for(int i=0;i<8;i++) pt[i]=chunk_dot(w[i],hc);
        wred_batch<8>(pt);
        if(lane==0){
          #pragma unroll
          for(int i=0;i<8;i++){ int s=wave+4*(g8*8+i); smL[s]=pt[i]+A.out_b[s]; }
        }
      }
      __syncthreads();
      if(wave==0){
        float l0=smL[lane], l1=smL[lane+64];
        float m  = wred_max(fmaxf(l0,l1));
        float pe = expf(l0-m)+expf(l1-m);
        float s1 = wred_sum(pe);
        float lse = m + logf(s1);
        float lp0 = l0-lse, lp1 = l1-lse;
        float m2  = wred_max(fmaxf(lp0,lp1));
        float p2  = expf(lp0-m2)+expf(lp1-m2);
        float s2  = wred_sum(p2);
        float lse2 = m2 + logf(s2);
        A.out[t*TDIM + lane]      = lp0;
        A.out[t*TDIM + 64 + lane] = lp1;
        int tg = A.tag_ids[t];
        float c = ((lane==tg)?(lse2-lp0):0.f) + ((lane+64==tg)?(lse2-lp1):0.f);
        c = wred_sum(c);
        if(tg != 0) loss += c;
      }
      __syncthreads();
    }
    if(tid==0) A.out[LSEQ*TDIM] = loss;
  } else if(p >= 0){
    // hoist dec_Whh and dec_Wih rows (<=4 each)
    Chunk wh[4], wi[4];
    #pragma unroll
    for(int i=0;i<4;i++){
      int r = wave+4*i; int rc = (r<nr)? r : 0;
      int le=rc/3, g=rc-le*3, row=g*HDIM+base+le;
      wh[i] = load_chunk(A.dec_Whh + (size_t)row*HDIM, lane);
      wi[i] = load_chunk(A.dec_Wih + (size_t)row*HDIM, lane);
    }
    for(int t=0;t<LSEQ;++t){
      if(t>0){ if(wave==0) wait_ctr(A.ctrH, tgt_prod((unsigned)t,lane), lane); }
      __syncthreads();
      stage_vec(lds_h, A.hbD + (t%3)*HDIM, tid);
      __syncthreads();
      float hc[16]; read16(lds_h, hc, lane);
      float ph[4];
      #pragma unroll
      for(int i=0;i<4;i++) ph[i]=chunk_dot(wh[i],hc);
      wred_batch<4>(ph);
      if(lane==0){
        #pragma unroll
        for(int i=0;i<4;i++){ int r=wave+4*i; if(r<nr) smr[r]=ph[i]; }
      }
      if(wave==0){
        wait_ctr(A.flagO, tgt_one((unsigned)(t+1),lane), lane);
        if(t>=3) wait_ctr(A.ctrW, tgt_lane0((unsigned)(t-2),lane), lane);
      }
      __syncthreads();
      stage_vec(lds_o, A.obD + (t&1)*HDIM, tid);
      __syncthreads();
      float oc[16]; read16(lds_o, oc, lane);
      float po[4];
      #pragma unroll
      for(int i=0;i<4;i++) po[i]=chunk_dot(wi[i],oc);
      wred_batch<4>(po);
      if(lane==0){
        #pragma unroll
        for(int i=0;i<4;i++){ int r=wave+4*i; if(r<nr) smr[32+r]=po[i]; }
      }
      __syncthreads();
      if(tid<ne){
        int j = base+tid;
        float gr=smr[tid*3]+A.dec_bhh[j],      gz=smr[tid*3+1]+A.dec_bhh[HDIM+j],
              gn=smr[tid*3+2]+A.dec_bhh[2*HDIM+j];
        float ir=smr[32+tid*3]+A.dec_bih[j],   iz=smr[32+tid*3+1]+A.dec_bih[HDIM+j],
              inn=smr[32+tid*3+2]+A.dec_bih[2*HDIM+j];
        float hj = lds_h[((j&15)*LSTR)+(j>>4)];
        float r_=sigm(ir+gr), z_=sigm(iz+gz);
        float n_=tanhf(inn+r_*gn);
        float h2=(1.f-z_)*n_+z_*hj;
        st_coh(&A.hbD[((t+1)%3)*HDIM+j], h2);
      }
      __syncthreads();
      if(tid==0) addc(A.ctrH, bid);
    }
  }
}

extern "C" void kernel_launch(void* const* d_in, const int* in_sizes, int n_in,
                              void* d_out, int out_size, void* d_ws, size_t ws_size,
                              hipStream_t stream){
  (void)in_sizes; (void)n_in; (void)out_size; (void)ws_size;
  KArgs A;
  A.input_ids = (const int*)d_in[0];
  A.tag_ids   = (const int*)d_in[1];
  A.word_embed= (const float*)d_in[2];
  A.enc_Wih   = (const float*)d_in[3];
  A.enc_Whh   = (const float*)d_in[4];
  A.enc_bih   = (const float*)d_in[5];
  A.enc_bhh   = (const float*)d_in[6];
  A.dec_embed = (const float*)d_in[7];
  A.attn_W    = (const float*)d_in[8];
  A.attn_b    = (const float*)d_in[9];
  A.comb_W    = (const float*)d_in[10];
  A.comb_b    = (const float*)d_in[11];
  A.dec_Wih   = (const float*)d_in[12];
  A.dec_Whh   = (const float*)d_in[13];
  A.dec_bih   = (const float*)d_in[14];
  A.dec_bhh   = (const float*)d_in[15];
  A.out_W     = (const float*)d_in[16];
  A.out_b     = (const float*)d_in[17];
  A.out       = (float*)d_out;

  unsigned* u = (unsigned*)d_ws;
  A.ctrP  = u;         // classes at +0,16,32,48
  A.ctrE  = u + 64;
  A.ctrM  = u + 128;
  A.ctrH  = u + 192;
  A.flagO = u + 256;
  A.ctrW  = u + 320;
  float* f = (float*)d_ws + 512;
  A.GI       = f; f += LSEQ*G3;
  A.attn_e   = f; f += LSEQ*LSEQ + 14;
  A.pre_comb = f; f += LSEQ*HDIM;
  A.MT       = f; f += LSEQ*HDIM;
  A.enc_outs = f; f += LSEQ*HDIM;
  A.hbE      = f; f += 2*HDIM;
  A.hbD      = f; f += 3*HDIM;
  A.obD      = f; f += 2*HDIM;

  (void)hipMemsetAsync(d_ws, 0, 2048, stream);
  void* args[] = { &A };
  (void)hipLaunchCooperativeKernel((const void*)seq2seq_kernel, dim3(256), dim3(256),
                                   args, 0, stream);
}

// Round 5
// 923.426 us; speedup vs baseline: 2.4833x; 1.2014x over previous
//
#include <hip/hip_runtime.h>
#include <cstdint>

// Seq2Seq GRU enc/dec with attention, batch=1, L=50, H=1024, T=128 (fp32).
// Persistent cooperative kernel, 256 WGs x 256 threads, 1 WG/CU.
// WG0..3 helpers (redundant aw + o slice), WG4 out-proj+loss (1 behind),
// WG5 idle, WG6..255 producers (own 4-5 h elements).
// All cross-WG data stores are write-through (sc0 sc1); ordering uses
// per-wave vmcnt(0) + RELAXED atomics (no release -> no buffer_wbl2).
// Counters spread over 8 cachelines to halve same-line RMW serialization.

#define HDIM 1024
#define LSEQ 50
#define TDIM 128
#define G3   3072
#define PB   6
#define LSTR 68

typedef float f32x4 __attribute__((ext_vector_type(4)));

struct KArgs {
  const int* input_ids; const int* tag_ids;
  const float* word_embed;
  const float* enc_Wih; const float* enc_Whh; const float* enc_bih; const float* enc_bhh;
  const float* dec_embed; const float* attn_W; const float* attn_b;
  const float* comb_W; const float* comb_b;
  const float* dec_Wih; const float* dec_Whh; const float* dec_bih; const float* dec_bhh;
  const float* out_W; const float* out_b;
  float* out;
  unsigned* ctrP; unsigned* ctrE; unsigned* ctrM; unsigned* ctrH; unsigned* flagO;
  unsigned* ctrW;
  float* GI;        // 50*3072
  float* attn_e;    // 50*50
  float* pre_comb;  // 50*1024
  float* MT;        // 50*1024 (MT[s*H+i])
  float* enc_outs;  // 50*1024
  float* hbE;       // 2*1024
  float* hbD;       // 3*1024
  float* obD;       // 2*1024
};

__device__ __forceinline__ void fence_vm(){
  asm volatile("s_waitcnt vmcnt(0)" ::: "memory");
}
__device__ __forceinline__ void st_coh(float* p, float v){
  __hip_atomic_store(p, v, __ATOMIC_RELAXED, __HIP_MEMORY_SCOPE_AGENT);
}
__device__ __forceinline__ void stf(unsigned* p, unsigned v){
  __hip_atomic_store(p, v, __ATOMIC_RELAXED, __HIP_MEMORY_SCOPE_AGENT);
}
__device__ __forceinline__ void addc(unsigned* base, int bid){
  __hip_atomic_fetch_add(base + (bid&7)*16, 1u, __ATOMIC_RELAXED, __HIP_MEMORY_SCOPE_AGENT);
}
__device__ __forceinline__ f32x4 coh_load4(const float* p){
  f32x4 v;
  asm volatile("global_load_dwordx4 %0, %1, off sc0 sc1\n\ts_waitcnt vmcnt(0)"
               : "=v"(v) : "v"(p) : "memory");
  return v;
}

template<int N>
__device__ __forceinline__ void wred_batch(float* v){
  #pragma unroll
  for(int o=32;o>0;o>>=1){
    #pragma unroll
    for(int i=0;i<N;i++) v[i] += __shfl_xor(v[i],o,64);
  }
}
__device__ __forceinline__ float wred_sum(float v){
  #pragma unroll
  for(int o=32;o>0;o>>=1) v += __shfl_xor(v,o,64);
  return v;
}
__device__ __forceinline__ float wred_max(float v){
  #pragma unroll
  for(int o=32;o>0;o>>=1) v = fmaxf(v,__shfl_xor(v,o,64));
  return v;
}

struct Chunk { float4 a,b,c,d; };
__device__ __forceinline__ Chunk load_chunk(const float* __restrict__ row, int lane){
  const float4* p = reinterpret_cast<const float4*>(row) + lane*4;
  Chunk w; w.a=p[0]; w.b=p[1]; w.c=p[2]; w.d=p[3]; return w;
}
__device__ __forceinline__ float chunk_dot(const Chunk& w, const float* hc){
  return w.a.x*hc[0]+w.a.y*hc[1]+w.a.z*hc[2]+w.a.w*hc[3]
       + w.b.x*hc[4]+w.b.y*hc[5]+w.b.z*hc[6]+w.b.w*hc[7]
       + w.c.x*hc[8]+w.c.y*hc[9]+w.c.z*hc[10]+w.c.w*hc[11]
       + w.d.x*hc[12]+w.d.y*hc[13]+w.d.z*hc[14]+w.d.w*hc[15];
}
__device__ __forceinline__ void load_vec16(const float* __restrict__ v, float* hc, int lane){
  const float4* p = reinterpret_cast<const float4*>(v) + lane*4;
  float4 x0=p[0],x1=p[1],x2=p[2],x3=p[3];
  hc[0]=x0.x; hc[1]=x0.y; hc[2]=x0.z; hc[3]=x0.w;
  hc[4]=x1.x; hc[5]=x1.y; hc[6]=x1.z; hc[7]=x1.w;
  hc[8]=x2.x; hc[9]=x2.y; hc[10]=x2.z; hc[11]=x2.w;
  hc[12]=x3.x; hc[13]=x3.y; hc[14]=x3.z; hc[15]=x3.w;
}
__device__ __forceinline__ float sigm(float x){ return 1.f/(1.f+expf(-x)); }

// stage 1024 floats: thread t coherent-loads g[4t..4t+3] -> padded LDS
// element j -> lds[(j&15)*LSTR + (j>>4)]
__device__ __forceinline__ void stage_vec(float* ldsb, const float* g, int tid){
  f32x4 v = coh_load4(g + 4*tid);
  int q = tid>>2, r4 = (tid&3)*4;
  ldsb[(r4+0)*LSTR+q]=v.x; ldsb[(r4+1)*LSTR+q]=v.y;
  ldsb[(r4+2)*LSTR+q]=v.z; ldsb[(r4+3)*LSTR+q]=v.w;
}
__device__ __forceinline__ void read16(const float* ldsb, float* hc, int lane){
  #pragma unroll
  for(int k=0;k<16;k++) hc[k]=ldsb[k*LSTR+lane];
}

// wave0 poll: lanes 0..7 check 8 spread counter lines >= tgt
__device__ __forceinline__ void wait_ctr(const unsigned* base, unsigned tgt, int lane){
  const unsigned* p = base + lane*16;
  for(;;){
    unsigned v = (lane<8)? __hip_atomic_load(p,__ATOMIC_RELAXED,__HIP_MEMORY_SCOPE_AGENT) : 0u;
    if(__all((int)(v>=tgt))) return;
    __builtin_amdgcn_s_sleep(2);
  }
}
// producers are bids 6..255: class=bid&7 -> counts {31,31,31,31,31,31,32,32}
__device__ __forceinline__ unsigned tgt_prod(unsigned mult,int lane){
  return (lane<8)? ((lane<6)?31u:32u)*mult : 0u;
}
__device__ __forceinline__ unsigned tgt_all(unsigned mult,int lane){
  return (lane<8)? 32u*mult : 0u;
}
__device__ __forceinline__ unsigned tgt_one(unsigned mult,int lane){
  return (lane<4)? mult : 0u;
}
__device__ __forceinline__ unsigned tgt_lane0(unsigned mult,int lane){
  return (lane==0)? mult : 0u;
}

__global__ __launch_bounds__(256,1) void seq2seq_kernel(KArgs A){
  const int bid = blockIdx.x, tid = threadIdx.x;
  const int wave = tid>>6, lane = tid&63;
  __shared__ float lds_h[16*LSTR+16];
  __shared__ float lds_o[16*LSTR+16];
  __shared__ float smr[64];
  __shared__ float smL[TDIM];
  __shared__ float awL[64];

  const int gv = bid*4 + wave;   // 0..1023

  // ================= prologue ================================================
  {
    const int r0 = gv*3;
    Chunk w0 = load_chunk(A.enc_Wih + (size_t)r0*HDIM, lane);
    Chunk w1 = load_chunk(A.enc_Wih + (size_t)(r0+1)*HDIM, lane);
    Chunk w2 = load_chunk(A.enc_Wih + (size_t)(r0+2)*HDIM, lane);
    float b0=A.enc_bih[r0], b1=A.enc_bih[r0+1], b2=A.enc_bih[r0+2];
    for(int te=0;te<LSEQ;++te){
      int tok = A.input_ids[te];
      float ec[16]; load_vec16(A.word_embed + (size_t)tok*HDIM, ec, lane);
      float d[3];
      d[0]=chunk_dot(w0,ec); d[1]=chunk_dot(w1,ec); d[2]=chunk_dot(w2,ec);
      wred_batch<3>(d);
      if(lane==0){
        st_coh(&A.GI[te*G3+r0],   d[0]+b0);
        st_coh(&A.GI[te*G3+r0+1], d[1]+b1);
        st_coh(&A.GI[te*G3+r0+2], d[2]+b2);
      }
    }
    Chunk wc = load_chunk(A.comb_W + (size_t)gv*2*HDIM, lane);
    float bc = A.comb_b[gv];
    Chunk wa; wa.a=make_float4(0,0,0,0); wa.b=wa.a; wa.c=wa.a; wa.d=wa.a;
    float ba = 0.f;
    if(gv < LSEQ){ wa = load_chunk(A.attn_W + (size_t)gv*2*HDIM, lane); ba = A.attn_b[gv]; }
    for(int t=0;t<LSEQ;++t){
      int tok = (t==0)?1:A.tag_ids[t-1];
      float ec[16]; load_vec16(A.dec_embed + (size_t)tok*HDIM, ec, lane);
      float d[2];
      d[0]=chunk_dot(wc,ec);
      d[1]=(gv<LSEQ)? chunk_dot(wa,ec) : 0.f;
      wred_batch<2>(d);
      if(lane==0){
        st_coh(&A.pre_comb[t*HDIM+gv], d[0]+bc);
        if(gv<LSEQ) st_coh(&A.attn_e[t*LSEQ+gv], d[1]+ba);
      }
    }
  }
  fence_vm();
  __syncthreads();
  if(tid==0) addc(A.ctrP, bid);
  if(wave==0) wait_ctr(A.ctrP, tgt_all(1,lane), lane);
  __syncthreads();

  // producer geometry
  const int p = bid - PB;
  int ne=0, base=0;
  if(p>=0){ ne=(p<24)?5:4; base=(p<24)? p*5 : 120+(p-24)*4; }
  const int nr = 3*ne;

  // ================= encoder =================================================
  if(p>=0){
    Chunk we[4];
    #pragma unroll
    for(int i=0;i<4;i++){
      int r = wave+4*i; int rc = (r<nr)? r : 0;
      int le=rc/3, g=rc-le*3, row=g*HDIM+base+le;
      we[i] = load_chunk(A.enc_Whh + (size_t)row*HDIM, lane);
    }
    for(int te=0;te<LSEQ;++te){
      if(te>0){
        if(wave==0) wait_ctr(A.ctrE, tgt_prod((unsigned)te,lane), lane);
        __syncthreads();
        stage_vec(lds_h, A.hbE + ((te-1)&1)*HDIM, tid);
      }
      __syncthreads();
      float hc[16];
      if(te>0) read16(lds_h, hc, lane);
      else     { for(int k=0;k<16;k++) hc[k]=0.f; }
      float part[4];
      #pragma unroll
      for(int i=0;i<4;i++) part[i]=chunk_dot(we[i],hc);
      wred_batch<4>(part);
      if(lane==0){
        #pragma unroll
        for(int i=0;i<4;i++){ int r=wave+4*i; if(r<nr) smr[r]=part[i]; }
      }
      __syncthreads();
      if(tid<ne){
        int j = base+tid;
        float gr=smr[tid*3]+A.enc_bhh[j], gz=smr[tid*3+1]+A.enc_bhh[HDIM+j],
              gn=smr[tid*3+2]+A.enc_bhh[2*HDIM+j];
        const float* GIr = A.GI + te*G3;
        float hj = (te>0)? lds_h[((j&15)*LSTR)+(j>>4)] : 0.f;
        float r_=sigm(GIr[j]+gr), z_=sigm(GIr[HDIM+j]+gz);
        float n_=tanhf(GIr[2*HDIM+j]+r_*gn);
        float h2=(1.f-z_)*n_+z_*hj;
        st_coh(&A.hbE[(te&1)*HDIM+j], h2);
        st_coh(&A.enc_outs[te*HDIM+j], h2);
        if(te==LSEQ-1) st_coh(&A.hbD[j], h2);
      }
      fence_vm();
      __syncthreads();
      if(tid==0) addc(A.ctrE, bid);
    }
  }

  // ================= MT = comb_W[:,H:] @ enc_outs^T ==========================
  if(wave==0) wait_ctr(A.ctrE, tgt_prod(LSEQ,lane), lane);
  __syncthreads();
  {
    Chunk wm = load_chunk(A.comb_W + (size_t)gv*2*HDIM + HDIM, lane);
    for(int sg=0;sg<10;++sg){
      float pt[5];
      #pragma unroll
      for(int j=0;j<5;j++){
        float ec[16]; load_vec16(A.enc_outs + (sg*5+j)*HDIM, ec, lane);
        pt[j]=chunk_dot(wm,ec);
      }
      wred_batch<5>(pt);
      if(lane==0){
        #pragma unroll
        for(int j=0;j<5;j++) st_coh(&A.MT[(sg*5+j)*HDIM+gv], pt[j]);
      }
    }
  }
  fence_vm();
  __syncthreads();
  if(tid==0) addc(A.ctrM, bid);
  if(wave==0) wait_ctr(A.ctrM, tgt_all(1,lane), lane);
  __syncthreads();

  // ================= decoder =================================================
  if(bid < 4){
    const int hi = bid;
    Chunk wa7[7], wa6[6];
    #pragma unroll
    for(int i=0;i<7;i++){ int s=wave+4*i;
      wa7[i]=load_chunk(A.attn_W+(size_t)s*2*HDIM+HDIM,lane); }
    #pragma unroll
    for(int i=0;i<6;i++){ int s=wave+28+4*i; int sc=(s<LSEQ)?s:0;
      wa6[i]=load_chunk(A.attn_W+(size_t)sc*2*HDIM+HDIM,lane); }
    for(int t=0;t<LSEQ;++t){
      if(t>0){ if(wave==0) wait_ctr(A.ctrH, tgt_prod((unsigned)t,lane), lane); }
      __syncthreads();
      stage_vec(lds_h, A.hbD + (t%3)*HDIM, tid);
      __syncthreads();
      float hc[16]; read16(lds_h, hc, lane);
      {
        float p7[7];
        #pragma unroll
        for(int i=0;i<7;i++) p7[i]=chunk_dot(wa7[i],hc);
        wred_batch<7>(p7);
        if(lane==0){
          #pragma unroll
          for(int i=0;i<7;i++){ int s=wave+4*i; smL[s]=p7[i]+A.attn_e[t*LSEQ+s]; }
        }
        float p6[6];
        #pragma unroll
        for(int i=0;i<6;i++) p6[i]=chunk_dot(wa6[i],hc);
        wred_batch<6>(p6);
        if(lane==0){
          #pragma unroll
          for(int i=0;i<6;i++){ int s=wave+28+4*i; if(s<LSEQ) smL[s]=p6[i]+A.attn_e[t*LSEQ+s]; }
        }
      }
      __syncthreads();
      if(wave==0){
        float l = (lane<LSEQ)? smL[lane] : -1e30f;
        float m = wred_max(l);
        float pe = (lane<LSEQ)? expf(l-m) : 0.f;
        float ss = wred_sum(pe);
        awL[lane] = (lane<LSEQ)? pe/ss : 0.f;
      }
      __syncthreads();
      {
        int i = hi*256 + tid;
        const float* Mi = A.MT + i;
        float acc = A.pre_comb[t*HDIM+i];
        #pragma unroll 10
        for(int s=0;s<LSEQ;++s) acc += Mi[s*HDIM]*awL[s];
        st_coh(&A.obD[(t&1)*HDIM+i], fmaxf(acc,0.f));
      }
      fence_vm();
      __syncthreads();
      if(tid==0) stf(A.flagO + hi*16, (unsigned)(t+1));
    }
  } else if(bid == 4){
    float loss = 0.f;
    for(int t=0;t<LSEQ;++t){
      if(wave==0) wait_ctr(A.ctrH, tgt_prod((unsigned)(t+1),lane), lane);
      __syncthreads();
      stage_vec(lds_h, A.hbD + ((t+1)%3)*HDIM, tid);
      __syncthreads();
      if(tid==0) stf(A.ctrW, (unsigned)(t+1));   // staged step t's h
      float hc[16]; read16(lds_h, hc, lane);
      for(int g8=0; g8<4; ++g8){
        Chunk w[8]; float pt[8];
        #pragma unroll
        for(int i=0;i<8;i++){ int s=wave+4*(g8*8+i);
          w[i]=load_chunk(A.out_W+(size_t)s*HDIM,lane); }
        #pragma unroll
        for(int i=0;i<8;i++) pt[i]=chunk_dot(w[i],hc);
        wred_batch<8>(pt);
        if(lane==0){
          #pragma unroll
          for(int i=0;i<8;i++){ int s=wave+4*(g8*8+i); smL[s]=pt[i]+A.out_b[s]; }
        }
      }
      __syncthreads();
      if(wave==0){
        float l0=smL[lane], l1=smL[lane+64];
        float m  = wred_max(fmaxf(l0,l1));
        float pe = expf(l0-m)+expf(l1-m);
        float s1 = wred_sum(pe);
        float lse = m + logf(s1);
        float lp0 = l0-lse, lp1 = l1-lse;
        float m2  = wred_max(fmaxf(lp0,lp1));
        float p2  = expf(lp0-m2)+expf(lp1-m2);
        float s2  = wred_sum(p2);
        float lse2 = m2 + logf(s2);
        A.out[t*TDIM + lane]      = lp0;
        A.out[t*TDIM + 64 + lane] = lp1;
        int tg = A.tag_ids[t];
        float c = ((lane==tg)?(lse2-lp0):0.f) + ((lane+64==tg)?(lse2-lp1):0.f);
        c = wred_sum(c);
        if(tg != 0) loss += c;
      }
      __syncthreads();
    }
    if(tid==0) A.out[LSEQ*TDIM] = loss;
  } else if(p >= 0){
    Chunk wh[4], wi[4];
    #pragma unroll
    for(int i=0;i<4;i++){
      int r = wave+4*i; int rc = (r<nr)? r : 0;
      int le=rc/3, g=rc-le*3, row=g*HDIM+base+le;
      wh[i] = load_chunk(A.dec_Whh + (size_t)row*HDIM, lane);
      wi[i] = load_chunk(A.dec_Wih + (size_t)row*HDIM, lane);
    }
    for(int t=0;t<LSEQ;++t){
      if(t>0){ if(wave==0) wait_ctr(A.ctrH, tgt_prod((unsigned)t,lane), lane); }
      __syncthreads();
      stage_vec(lds_h, A.hbD + (t%3)*HDIM, tid);
      __syncthreads();
      float hc[16]; read16(lds_h, hc, lane);
      float ph[4];
      #pragma unroll
      for(int i=0;i<4;i++) ph[i]=chunk_dot(wh[i],hc);
      wred_batch<4>(ph);
      if(lane==0){
        #pragma unroll
        for(int i=0;i<4;i++){ int r=wave+4*i; if(r<nr) smr[r]=ph[i]; }
      }
      if(wave==0){
        wait_ctr(A.flagO, tgt_one((unsigned)(t+1),lane), lane);
        if(t>=3) wait_ctr(A.ctrW, tgt_lane0((unsigned)(t-2),lane), lane);
      }
      __syncthreads();
      stage_vec(lds_o, A.obD + (t&1)*HDIM, tid);
      __syncthreads();
      float oc[16]; read16(lds_o, oc, lane);
      float po[4];
      #pragma unroll
      for(int i=0;i<4;i++) po[i]=chunk_dot(wi[i],oc);
      wred_batch<4>(po);
      if(lane==0){
        #pragma unroll
        for(int i=0;i<4;i++){ int r=wave+4*i; if(r<nr) smr[32+r]=po[i]; }
      }
      __syncthreads();
      if(tid<ne){
        int j = base+tid;
        float gr=smr[tid*3]+A.dec_bhh[j],      gz=smr[tid*3+1]+A.dec_bhh[HDIM+j],
              gn=smr[tid*3+2]+A.dec_bhh[2*HDIM+j];
        float ir=smr[32+tid*3]+A.dec_bih[j],   iz=smr[32+tid*3+1]+A.dec_bih[HDIM+j],
              inn=smr[32+tid*3+2]+A.dec_bih[2*HDIM+j];
        float hj = lds_h[((j&15)*LSTR)+(j>>4)];
        float r_=sigm(ir+gr), z_=sigm(iz+gz);
        float n_=tanhf(inn+r_*gn);
        float h2=(1.f-z_)*n_+z_*hj;
        st_coh(&A.hbD[((t+1)%3)*HDIM+j], h2);
      }
      fence_vm();
      __syncthreads();
      if(tid==0) addc(A.ctrH, bid);
    }
  }
}

extern "C" void kernel_launch(void* const* d_in, const int* in_sizes, int n_in,
                              void* d_out, int out_size, void* d_ws, size_t ws_size,
                              hipStream_t stream){
  (void)in_sizes; (void)n_in; (void)out_size; (void)ws_size;
  KArgs A;
  A.input_ids = (const int*)d_in[0];
  A.tag_ids   = (const int*)d_in[1];
  A.word_embed= (const float*)d_in[2];
  A.enc_Wih   = (const float*)d_in[3];
  A.enc_Whh   = (const float*)d_in[4];
  A.enc_bih   = (const float*)d_in[5];
  A.enc_bhh   = (const float*)d_in[6];
  A.dec_embed = (const float*)d_in[7];
  A.attn_W    = (const float*)d_in[8];
  A.attn_b    = (const float*)d_in[9];
  A.comb_W    = (const float*)d_in[10];
  A.comb_b    = (const float*)d_in[11];
  A.dec_Wih   = (const float*)d_in[12];
  A.dec_Whh   = (const float*)d_in[13];
  A.dec_bih   = (const float*)d_in[14];
  A.dec_bhh   = (const float*)d_in[15];
  A.out_W     = (const float*)d_in[16];
  A.out_b     = (const float*)d_in[17];
  A.out       = (float*)d_out;

  unsigned* u = (unsigned*)d_ws;
  A.ctrP  = u;          // 8 classes at stride 16 u (64B lines)
  A.ctrE  = u + 128;
  A.ctrM  = u + 256;
  A.ctrH  = u + 384;
  A.flagO = u + 512;    // 4 lines
  A.ctrW  = u + 576;    // 1 line
  float* f = (float*)d_ws + 1024;   // 4096 B offset
  A.GI       = f; f += LSEQ*G3;
  A.attn_e   = f; f += LSEQ*LSEQ + 14;
  A.pre_comb = f; f += LSEQ*HDIM;
  A.MT       = f; f += LSEQ*HDIM;
  A.enc_outs = f; f += LSEQ*HDIM;
  A.hbE      = f; f += 2*HDIM;
  A.hbD      = f; f += 3*HDIM;
  A.obD      = f; f += 2*HDIM;

  (void)hipMemsetAsync(d_ws, 0, 4096, stream);
  void* args[] = { &A };
  (void)hipLaunchCooperativeKernel((const void*)seq2seq_kernel, dim3(256), dim3(256),
                                   args, 0, stream);
}

// Round 6
// 620.257 us; speedup vs baseline: 3.6970x; 1.4888x over previous
//
#include <hip/hip_runtime.h>
#include <cstdint>

// Seq2Seq GRU enc/dec with attention, batch=1, L=50, H=1024, T=128 (fp32).
// Persistent cooperative kernel, 256 WGs x 256 threads.
// Sync via VALUE TAGS: low 5 mantissa bits of each cross-WG float carry the
// step epoch; consumers retry coherent loads until tags match (load == poll).
// Roles: WG0..3 helpers (redundant aw + o slice), WG4 logit-collect+loss,
// WG6..133 producers (8 h-elems each, weights in VGPRs),
// WG134..149 out-proj slices (8 rows each), rest exit after MT.

#define HDIM 1024
#define LSEQ 50
#define TDIM 128
#define G3   3072
#define PB   6
#define NPROD 128
#define LSTR 68

typedef float f32x4 __attribute__((ext_vector_type(4)));

struct KArgs {
  const int* input_ids; const int* tag_ids;
  const float* word_embed;
  const float* enc_Wih; const float* enc_Whh; const float* enc_bih; const float* enc_bhh;
  const float* dec_embed; const float* attn_W; const float* attn_b;
  const float* comb_W; const float* comb_b;
  const float* dec_Wih; const float* dec_Whh; const float* dec_bih; const float* dec_bhh;
  const float* out_W; const float* out_b;
  float* out;
  unsigned* ctrP; unsigned* ctrE; unsigned* ctrM; unsigned* ctrO; unsigned* ctrV;
  float* hbE;      // 2*1024 tagged
  float* hbD;      // 3*1024 tagged
  float* obD;      // 2*1024 tagged
  float* logits;   // 2*128  tagged
  float* GI;       // 50*3072
  float* attn_e;   // 50*50
  float* pre_comb; // 50*1024
  float* MT;       // 50*1024
  float* enc_outs; // 50*1024
};

__device__ __forceinline__ void fence_vm(){
  asm volatile("s_waitcnt vmcnt(0)" ::: "memory");
}
__device__ __forceinline__ void st_coh(float* p, float v){
  __hip_atomic_store(p, v, __ATOMIC_RELAXED, __HIP_MEMORY_SCOPE_AGENT);
}
__device__ __forceinline__ void st_tag(float* p, float v, unsigned tag){
  unsigned b = (__float_as_uint(v) & ~31u) | tag;
  st_coh(p, __uint_as_float(b));
}
__device__ __forceinline__ void stf(unsigned* p, unsigned v){
  __hip_atomic_store(p, v, __ATOMIC_RELAXED, __HIP_MEMORY_SCOPE_AGENT);
}
__device__ __forceinline__ unsigned ldu(const unsigned* p){
  return __hip_atomic_load(p, __ATOMIC_RELAXED, __HIP_MEMORY_SCOPE_AGENT);
}
__device__ __forceinline__ void addc(unsigned* base, int bid){
  __hip_atomic_fetch_add(base + (bid&7)*16, 1u, __ATOMIC_RELAXED, __HIP_MEMORY_SCOPE_AGENT);
}
__device__ __forceinline__ void addc0(unsigned* base){
  __hip_atomic_fetch_add(base, 1u, __ATOMIC_RELAXED, __HIP_MEMORY_SCOPE_AGENT);
}
__device__ __forceinline__ f32x4 coh_load4(const float* p){
  f32x4 v;
  asm volatile("global_load_dwordx4 %0, %1, off sc0 sc1\n\ts_waitcnt vmcnt(0)"
               : "=v"(v) : "v"(p) : "memory");
  return v;
}

template<int N>
__device__ __forceinline__ void wred_batch(float* v){
  #pragma unroll
  for(int o=32;o>0;o>>=1){
    #pragma unroll
    for(int i=0;i<N;i++) v[i] += __shfl_xor(v[i],o,64);
  }
}
__device__ __forceinline__ float wred_sum(float v){
  #pragma unroll
  for(int o=32;o>0;o>>=1) v += __shfl_xor(v,o,64);
  return v;
}
__device__ __forceinline__ float wred_max(float v){
  #pragma unroll
  for(int o=32;o>0;o>>=1) v = fmaxf(v,__shfl_xor(v,o,64));
  return v;
}

struct Chunk { float4 a,b,c,d; };
__device__ __forceinline__ Chunk load_chunk(const float* __restrict__ row, int lane){
  const float4* p = reinterpret_cast<const float4*>(row) + lane*4;
  Chunk w; w.a=p[0]; w.b=p[1]; w.c=p[2]; w.d=p[3]; return w;
}
__device__ __forceinline__ float chunk_dot(const Chunk& w, const float* hc){
  return w.a.x*hc[0]+w.a.y*hc[1]+w.a.z*hc[2]+w.a.w*hc[3]
       + w.b.x*hc[4]+w.b.y*hc[5]+w.b.z*hc[6]+w.b.w*hc[7]
       + w.c.x*hc[8]+w.c.y*hc[9]+w.c.z*hc[10]+w.c.w*hc[11]
       + w.d.x*hc[12]+w.d.y*hc[13]+w.d.z*hc[14]+w.d.w*hc[15];
}
__device__ __forceinline__ void load_vec16(const float* __restrict__ v, float* hc, int lane){
  const float4* p = reinterpret_cast<const float4*>(v) + lane*4;
  float4 x0=p[0],x1=p[1],x2=p[2],x3=p[3];
  hc[0]=x0.x; hc[1]=x0.y; hc[2]=x0.z; hc[3]=x0.w;
  hc[4]=x1.x; hc[5]=x1.y; hc[6]=x1.z; hc[7]=x1.w;
  hc[8]=x2.x; hc[9]=x2.y; hc[10]=x2.z; hc[11]=x2.w;
  hc[12]=x3.x; hc[13]=x3.y; hc[14]=x3.z; hc[15]=x3.w;
}
__device__ __forceinline__ float sigm(float x){ return 1.f/(1.f+expf(-x)); }

// retry-stage 1024 tagged floats into transposed LDS; element j at
// lds[(j&15)*LSTR + (j>>4)]; per-thread retry until all 4 tags match.
template<int SLP>
__device__ __forceinline__ void stage_tag(float* ldsb, const float* g, int tid, unsigned tag){
  const float* p = g + 4*tid;
  f32x4 v;
  for(;;){
    v = coh_load4(p);
    unsigned m = ((__float_as_uint(v.x)&31u)^tag) | ((__float_as_uint(v.y)&31u)^tag)
               | ((__float_as_uint(v.z)&31u)^tag) | ((__float_as_uint(v.w)&31u)^tag);
    if(m==0u) break;
    if(SLP) __builtin_amdgcn_s_sleep(SLP);
  }
  int q = tid>>2, r4 = (tid&3)*4;
  ldsb[(r4+0)*LSTR+q]=v.x; ldsb[(r4+1)*LSTR+q]=v.y;
  ldsb[(r4+2)*LSTR+q]=v.z; ldsb[(r4+3)*LSTR+q]=v.w;
}
__device__ __forceinline__ void read16(const float* ldsb, float* hc, int lane){
  #pragma unroll
  for(int k=0;k<16;k++) hc[k]=ldsb[k*LSTR+lane];
}

// barrier counters: 8 spread lines, lanes 0..7 poll
__device__ __forceinline__ void wait8(const unsigned* base, unsigned n, int lane){
  const unsigned* p = base + lane*16;
  for(;;){
    unsigned v = (lane<8)? ldu(p) : 0xFFFFFFFFu;
    if(__all((int)(v>=n))) return;
    __builtin_amdgcn_s_sleep(8);
  }
}

__global__ __launch_bounds__(256,1) void seq2seq_kernel(KArgs A){
  const int bid = blockIdx.x, tid = threadIdx.x;
  const int wave = tid>>6, lane = tid&63;
  __shared__ float lds_h[16*LSTR+16];
  __shared__ float lds_o[16*LSTR+16];
  __shared__ float smr[64];
  __shared__ float smL[TDIM];
  __shared__ float awL[64];

  const int gv = bid*4 + wave;   // 0..1023

  // ================= prologue: token-dependent precompute ====================
  {
    const int r0 = gv*3;
    Chunk w0 = load_chunk(A.enc_Wih + (size_t)r0*HDIM, lane);
    Chunk w1 = load_chunk(A.enc_Wih + (size_t)(r0+1)*HDIM, lane);
    Chunk w2 = load_chunk(A.enc_Wih + (size_t)(r0+2)*HDIM, lane);
    float b0=A.enc_bih[r0], b1=A.enc_bih[r0+1], b2=A.enc_bih[r0+2];
    for(int te=0;te<LSEQ;++te){
      int tok = A.input_ids[te];
      float ec[16]; load_vec16(A.word_embed + (size_t)tok*HDIM, ec, lane);
      float d[3];
      d[0]=chunk_dot(w0,ec); d[1]=chunk_dot(w1,ec); d[2]=chunk_dot(w2,ec);
      wred_batch<3>(d);
      if(lane==0){
        st_coh(&A.GI[te*G3+r0],   d[0]+b0);
        st_coh(&A.GI[te*G3+r0+1], d[1]+b1);
        st_coh(&A.GI[te*G3+r0+2], d[2]+b2);
      }
    }
    Chunk wc = load_chunk(A.comb_W + (size_t)gv*2*HDIM, lane);
    float bc = A.comb_b[gv];
    Chunk wa; wa.a=make_float4(0,0,0,0); wa.b=wa.a; wa.c=wa.a; wa.d=wa.a;
    float ba = 0.f;
    if(gv < LSEQ){ wa = load_chunk(A.attn_W + (size_t)gv*2*HDIM, lane); ba = A.attn_b[gv]; }
    for(int t=0;t<LSEQ;++t){
      int tok = (t==0)?1:A.tag_ids[t-1];
      float ec[16]; load_vec16(A.dec_embed + (size_t)tok*HDIM, ec, lane);
      float d[2];
      d[0]=chunk_dot(wc,ec);
      d[1]=(gv<LSEQ)? chunk_dot(wa,ec) : 0.f;
      wred_batch<2>(d);
      if(lane==0){
        st_coh(&A.pre_comb[t*HDIM+gv], d[0]+bc);
        if(gv<LSEQ) st_coh(&A.attn_e[t*LSEQ+gv], d[1]+ba);
      }
    }
  }
  fence_vm();
  __syncthreads();
  if(tid==0) addc(A.ctrP, bid);
  if(wave==0) wait8(A.ctrP, 32u, lane);
  __syncthreads();

  // producer geometry: bids 6..133 own 8 h-elements each
  const int p = bid - PB;
  const bool is_prod = (p>=0 && p<NPROD);
  const int base = is_prod ? p*8 : 0;

  // ================= encoder: 50 sequential GRU steps (producers) ===========
  if(is_prod){
    Chunk we[6];
    #pragma unroll
    for(int i=0;i<6;i++){
      int r = wave + 4*i;                 // 0..23 ; r = 3*le + g
      int le=r/3, g=r-3*le, row=g*HDIM+base+le;
      we[i] = load_chunk(A.enc_Whh + (size_t)row*HDIM, lane);
    }
    for(int te=0;te<LSEQ;++te){
      float hc[16];
      if(te>0){
        stage_tag<1>(lds_h, A.hbE + ((te-1)&1)*HDIM, tid, (unsigned)(te&31));
        __syncthreads();
        read16(lds_h, hc, lane);
      } else {
        for(int k=0;k<16;k++) hc[k]=0.f;
      }
      float part[6];
      #pragma unroll
      for(int i=0;i<6;i++) part[i]=chunk_dot(we[i],hc);
      wred_batch<6>(part);
      if(lane==0){
        #pragma unroll
        for(int i=0;i<6;i++) smr[wave+4*i]=part[i];
      }
      __syncthreads();
      if(tid<8){
        int j = base+tid;
        float gr=smr[tid*3]+A.enc_bhh[j], gz=smr[tid*3+1]+A.enc_bhh[HDIM+j],
              gn=smr[tid*3+2]+A.enc_bhh[2*HDIM+j];
        const float* GIr = A.GI + te*G3;
        float hj = (te>0)? lds_h[((j&15)*LSTR)+(j>>4)] : 0.f;
        float r_=sigm(GIr[j]+gr), z_=sigm(GIr[HDIM+j]+gz);
        float n_=tanhf(GIr[2*HDIM+j]+r_*gn);
        float h2=(1.f-z_)*n_+z_*hj;
        st_tag(&A.hbE[(te&1)*HDIM+j], h2, (unsigned)((te+1)&31));
        st_coh(&A.enc_outs[te*HDIM+j], h2);
        if(te==LSEQ-1) st_tag(&A.hbD[j], h2, 0u);
      }
      __syncthreads();
    }
    fence_vm();
    __syncthreads();
    if(tid==0) addc(A.ctrE, bid);
  }
  if(wave==0) wait8(A.ctrE, 16u, lane);   // 128 producers -> 16 per class
  __syncthreads();

  // ================= MT = comb_W[:,H:] @ enc_outs^T ==========================
  {
    Chunk wm = load_chunk(A.comb_W + (size_t)gv*2*HDIM + HDIM, lane);
    for(int sg=0;sg<10;++sg){
      float pt[5];
      #pragma unroll
      for(int j=0;j<5;j++){
        float ec[16]; load_vec16(A.enc_outs + (sg*5+j)*HDIM, ec, lane);
        pt[j]=chunk_dot(wm,ec);
      }
      wred_batch<5>(pt);
      if(lane==0){
        #pragma unroll
        for(int j=0;j<5;j++) st_coh(&A.MT[(sg*5+j)*HDIM+gv], pt[j]);
      }
    }
  }
  fence_vm();
  __syncthreads();
  if(tid==0) addc(A.ctrM, bid);
  if(bid==5 || bid>=150) return;          // spectators done
  if(wave==0) wait8(A.ctrM, 32u, lane);
  __syncthreads();

  // ================= decoder: 50 steps =======================================
  if(bid < 4){
    // helpers: redundant aw + o slice of 256 (tagged store, no flags)
    const int hi = bid;
    Chunk wa7[7], wa6[6];
    #pragma unroll
    for(int i=0;i<7;i++){ int s=wave+4*i;
      wa7[i]=load_chunk(A.attn_W+(size_t)s*2*HDIM+HDIM,lane); }
    #pragma unroll
    for(int i=0;i<6;i++){ int s=wave+28+4*i; int sc=(s<LSEQ)?s:0;
      wa6[i]=load_chunk(A.attn_W+(size_t)sc*2*HDIM+HDIM,lane); }
    for(int t=0;t<LSEQ;++t){
      stage_tag<0>(lds_h, A.hbD + (t%3)*HDIM, tid, (unsigned)(t&31));
      __syncthreads();
      float hc[16]; read16(lds_h, hc, lane);
      {
        float p7[7];
        #pragma unroll
        for(int i=0;i<7;i++) p7[i]=chunk_dot(wa7[i],hc);
        wred_batch<7>(p7);
        if(lane==0){
          #pragma unroll
          for(int i=0;i<7;i++){ int s=wave+4*i; smL[s]=p7[i]+A.attn_e[t*LSEQ+s]; }
        }
        float p6[6];
        #pragma unroll
        for(int i=0;i<6;i++) p6[i]=chunk_dot(wa6[i],hc);
        wred_batch<6>(p6);
        if(lane==0){
          #pragma unroll
          for(int i=0;i<6;i++){ int s=wave+28+4*i; if(s<LSEQ) smL[s]=p6[i]+A.attn_e[t*LSEQ+s]; }
        }
      }
      __syncthreads();
      if(wave==0){
        float l = (lane<LSEQ)? smL[lane] : -1e30f;
        float m = wred_max(l);
        float pe = (lane<LSEQ)? expf(l-m) : 0.f;
        float ss = wred_sum(pe);
        awL[lane] = (lane<LSEQ)? pe/ss : 0.f;
      }
      __syncthreads();
      {
        int i = hi*256 + tid;
        const float* Mi = A.MT + i;
        float acc = A.pre_comb[t*HDIM+i];
        #pragma unroll 10
        for(int s=0;s<LSEQ;++s) acc += Mi[s*HDIM]*awL[s];
        st_tag(&A.obD[(t&1)*HDIM+i], fmaxf(acc,0.f), (unsigned)(t&31));
      }
      __syncthreads();
    }
  } else if(bid == 4){
    // collect tagged logits, double log_softmax, out + loss
    float loss = 0.f;
    for(int t=0;t<LSEQ;++t){
      if(tid<32){
        const float* pp = A.logits + (t&1)*TDIM + 4*tid;
        const unsigned tg = (unsigned)(t&31);
        f32x4 v;
        for(;;){
          v = coh_load4(pp);
          unsigned m = ((__float_as_uint(v.x)&31u)^tg) | ((__float_as_uint(v.y)&31u)^tg)
                     | ((__float_as_uint(v.z)&31u)^tg) | ((__float_as_uint(v.w)&31u)^tg);
          if(m==0u) break;
          __builtin_amdgcn_s_sleep(1);
        }
        smL[4*tid]=v.x; smL[4*tid+1]=v.y; smL[4*tid+2]=v.z; smL[4*tid+3]=v.w;
      }
      __syncthreads();
      if(tid==0) stf(A.ctrV, (unsigned)(t+1));   // epoch t logits consumed
      if(wave==0){
        float l0=smL[lane], l1=smL[lane+64];
        float m  = wred_max(fmaxf(l0,l1));
        float pe = expf(l0-m)+expf(l1-m);
        float s1 = wred_sum(pe);
        float lse = m + logf(s1);
        float lp0 = l0-lse, lp1 = l1-lse;
        float m2  = wred_max(fmaxf(lp0,lp1));
        float p2  = expf(lp0-m2)+expf(lp1-m2);
        float s2  = wred_sum(p2);
        float lse2 = m2 + logf(s2);
        A.out[t*TDIM + lane]      = lp0;
        A.out[t*TDIM + 64 + lane] = lp1;
        int tg2 = A.tag_ids[t];
        float c = ((lane==tg2)?(lse2-lp0):0.f) + ((lane+64==tg2)?(lse2-lp1):0.f);
        c = wred_sum(c);
        if(tg2 != 0) loss += c;
      }
      __syncthreads();
    }
    if(tid==0) A.out[LSEQ*TDIM] = loss;
  } else if(is_prod){
    // producers: gh dots overlap helper aw/o; then o-stage, gi, combine
    Chunk wh[6], wi[6];
    #pragma unroll
    for(int i=0;i<6;i++){
      int r = wave + 4*i;
      int le=r/3, g=r-3*le, row=g*HDIM+base+le;
      wh[i] = load_chunk(A.dec_Whh + (size_t)row*HDIM, lane);
      wi[i] = load_chunk(A.dec_Wih + (size_t)row*HDIM, lane);
    }
    for(int t=0;t<LSEQ;++t){
      stage_tag<2>(lds_h, A.hbD + (t%3)*HDIM, tid, (unsigned)(t&31));
      __syncthreads();
      float hc[16]; read16(lds_h, hc, lane);
      float ph[6];
      #pragma unroll
      for(int i=0;i<6;i++) ph[i]=chunk_dot(wh[i],hc);
      wred_batch<6>(ph);
      if(lane==0){
        #pragma unroll
        for(int i=0;i<6;i++) smr[wave+4*i]=ph[i];
      }
      if(wave==0 && t>=3){
        const unsigned tgt = 16u*(unsigned)(t-2);   // out-proj staged epoch t-2
        for(;;){
          unsigned v = (lane==0)? ldu(A.ctrO) : tgt;
          if(__all((int)(v>=tgt))) break;
          __builtin_amdgcn_s_sleep(2);
        }
      }
      __syncthreads();
      stage_tag<2>(lds_o, A.obD + (t&1)*HDIM, tid, (unsigned)(t&31));
      __syncthreads();
      float oc[16]; read16(lds_o, oc, lane);
      float po[6];
      #pragma unroll
      for(int i=0;i<6;i++) po[i]=chunk_dot(wi[i],oc);
      wred_batch<6>(po);
      if(lane==0){
        #pragma unroll
        for(int i=0;i<6;i++) smr[32+wave+4*i]=po[i];
      }
      __syncthreads();
      if(tid<8){
        int j = base+tid;
        float gr=smr[tid*3]+A.dec_bhh[j],      gz=smr[tid*3+1]+A.dec_bhh[HDIM+j],
              gn=smr[tid*3+2]+A.dec_bhh[2*HDIM+j];
        float ir=smr[32+tid*3]+A.dec_bih[j],   iz=smr[32+tid*3+1]+A.dec_bih[HDIM+j],
              inn=smr[32+tid*3+2]+A.dec_bih[2*HDIM+j];
        float hj = lds_h[((j&15)*LSTR)+(j>>4)];
        float r_=sigm(ir+gr), z_=sigm(iz+gz);
        float n_=tanhf(inn+r_*gn);
        float h2=(1.f-z_)*n_+z_*hj;
        st_tag(&A.hbD[((t+1)%3)*HDIM+j], h2, (unsigned)((t+1)&31));
      }
      __syncthreads();
    }
  } else if(bid>=134 && bid<150){
    // out-proj: 8 rows each, 2 rows/wave in VGPRs; tagged logit stores
    const int ob = bid-134;
    Chunk wo[2];
    float bo[2];
    #pragma unroll
    for(int i=0;i<2;i++){
      int row = ob*8 + wave*2 + i;
      wo[i]=load_chunk(A.out_W+(size_t)row*HDIM,lane);
      bo[i]=A.out_b[row];
    }
    for(int t=0;t<LSEQ;++t){
      stage_tag<4>(lds_h, A.hbD + ((t+1)%3)*HDIM, tid, (unsigned)((t+1)&31));
      __syncthreads();
      if(tid==0) addc0(A.ctrO);            // "I staged epoch t+1"
      float hc[16]; read16(lds_h, hc, lane);
      float pt[2]={chunk_dot(wo[0],hc),chunk_dot(wo[1],hc)};
      wred_batch<2>(pt);
      if(wave==0 && t>=2){
        const unsigned tgt = (unsigned)(t-1);  // WG4 consumed epoch t-2
        for(;;){
          unsigned v = (lane==0)? ldu(A.ctrV) : tgt;
          if(__all((int)(v>=tgt))) break;
          __builtin_amdgcn_s_sleep(4);
        }
      }
      __syncthreads();
      if(lane==0){
        int row = ob*8 + wave*2;
        st_tag(&A.logits[(t&1)*TDIM + row],   pt[0]+bo[0], (unsigned)(t&31));
        st_tag(&A.logits[(t&1)*TDIM + row+1], pt[1]+bo[1], (unsigned)(t&31));
      }
      __syncthreads();
    }
  }
}

extern "C" void kernel_launch(void* const* d_in, const int* in_sizes, int n_in,
                              void* d_out, int out_size, void* d_ws, size_t ws_size,
                              hipStream_t stream){
  (void)in_sizes; (void)n_in; (void)out_size; (void)ws_size;
  KArgs A;
  A.input_ids = (const int*)d_in[0];
  A.tag_ids   = (const int*)d_in[1];
  A.word_embed= (const float*)d_in[2];
  A.enc_Wih   = (const float*)d_in[3];
  A.enc_Whh   = (const float*)d_in[4];
  A.enc_bih   = (const float*)d_in[5];
  A.enc_bhh   = (const float*)d_in[6];
  A.dec_embed = (const float*)d_in[7];
  A.attn_W    = (const float*)d_in[8];
  A.attn_b    = (const float*)d_in[9];
  A.comb_W    = (const float*)d_in[10];
  A.comb_b    = (const float*)d_in[11];
  A.dec_Wih   = (const float*)d_in[12];
  A.dec_Whh   = (const float*)d_in[13];
  A.dec_bih   = (const float*)d_in[14];
  A.dec_bhh   = (const float*)d_in[15];
  A.out_W     = (const float*)d_in[16];
  A.out_b     = (const float*)d_in[17];
  A.out       = (float*)d_out;

  unsigned* u = (unsigned*)d_ws;
  A.ctrP = u;          // 8 lines (stride 16u)
  A.ctrE = u + 128;
  A.ctrM = u + 256;
  A.ctrO = u + 384;    // single line
  A.ctrV = u + 448;    // single line
  float* f = (float*)d_ws + 1024;   // byte 4096
  A.hbE    = f; f += 2*HDIM;        // tagged region start (byte 4096)
  A.hbD    = f; f += 3*HDIM;
  A.obD    = f; f += 2*HDIM;
  A.logits = f; f += 2*TDIM;        // tagged region end: 7424 floats
  A.GI       = f; f += LSEQ*G3;
  A.attn_e   = f; f += LSEQ*LSEQ + 14;
  A.pre_comb = f; f += LSEQ*HDIM;
  A.MT       = f; f += LSEQ*HDIM;
  A.enc_outs = f; f += LSEQ*HDIM;

  (void)hipMemsetAsync(d_ws, 0, 4096, stream);                        // counters
  (void)hipMemsetAsync((char*)d_ws + 4096, 0xFF, 7424*4, stream);     // tag bufs -> tag 31
  void* args[] = { &A };
  (void)hipLaunchCooperativeKernel((const void*)seq2seq_kernel, dim3(256), dim3(256),
                                   args, 0, stream);
}